// Round 13
// baseline (1549.764 us; speedup 1.0000x reference)
//
#include <hip/hip_runtime.h>
#include <hip/hip_bf16.h>

#define NN 100000
#define NE 3200000
#define NL 1000000
#define NBC 98                          // coarse buckets (dst >> 10)
#define NPBC 1024                       // nodes per coarse bucket
#define CAPC 34816                      // per-bucket capacity (mean 32768, +11 sigma)
#define RCAP 64                         // LDS ring entries per bucket (= flush chunk)

__device__ __forceinline__ long long nt_ll(const void* p) {
    return __builtin_nontemporal_load((const long long*)p);
}

// ---------------- zero int buffer ----------------
__global__ void k_zero(int* __restrict__ p, int n) {
    int i = blockIdx.x * blockDim.x + threadIdx.x;
    if (i < n) p[i] = 0;
}

// ------- LDS-staged binning: 98 coarse buckets, wave-cooperative 512B flushes -------
__global__ __launch_bounds__(256) void k_bin(const int* __restrict__ src,
                                             const int* __restrict__ dst,
                                             const float* __restrict__ w,
                                             int* __restrict__ gcnt,
                                             long long* __restrict__ binned,
                                             int e_cnt, int epb) {
    __shared__ long long ring[NBC * RCAP];     // 98*64*8 = 50176 B
    __shared__ int lvl[128], ladd[128];        // sized >= NBC
    __shared__ int notdone;
    int t = threadIdx.x, wv = t >> 6, lane = t & 63;
    if (t < 128) { lvl[t] = 0; ladd[t] = 0; }
    __syncthreads();
    int e0 = blockIdx.x * epb;
    int nbatch = (epb + 255) >> 8;
    for (int it = 0; it < nbatch; ++it) {
        int off = it * 256 + t;
        int e = e0 + off;
        bool have = (off < epb) && (e < e_cnt);
        long long ent = 0; int b = 0;
        if (have) {
            int d = __builtin_nontemporal_load(dst + e);
            int s = __builtin_nontemporal_load(src + e);
            float wf = __builtin_nontemporal_load(w + e);
            b = d >> 10;                       // 0..97
            ent = (unsigned int)(s | ((d & 1023) << 17)) |
                  ((long long)__float_as_int(wf) << 32);
        }
        // place/flush rounds; watchdog provably unreached (each stuck round
        // flushes 64 entries from any full bucket; <=6 rounds per 256-edge batch)
        for (int round = 0; round < 32; ++round) {
            if (t == 0) notdone = 0;
            __syncthreads();
            int rank = 0;
            if (have) rank = atomicAdd(&ladd[b], 1);
            __syncthreads();
            if (have) {
                int pos = lvl[b] + rank;
                if (pos < RCAP) { ring[b * RCAP + pos] = ent; have = false; }
                else notdone = 1;
            }
            __syncthreads();
            if (t < 128) {
                int nl = lvl[t] + ladd[t];
                lvl[t] = nl > RCAP ? RCAP : nl;
                ladd[t] = 0;
            }
            __syncthreads();
            // wave wv owns buckets bb ≡ wv (mod 4): flush full 64-entry (512B) chunks
            for (int bb = wv; bb < NBC; bb += 4) {
                if (lvl[bb] >= RCAP) {
                    int g = 0;
                    if (lane == 0) g = atomicAdd(&gcnt[bb], RCAP);
                    g = __shfl(g, 0, 64);
                    if (g + lane < CAPC)
                        binned[(size_t)bb * CAPC + g + lane] = ring[bb * RCAP + lane];
                    if (lane == 0) lvl[bb] = 0;
                }
            }
            __syncthreads();
            if (!notdone) break;
        }
    }
    // drain leftovers (coalesced, <= RCAP=64 entries per bucket)
    for (int bb = wv; bb < NBC; bb += 4) {
        int L = lvl[bb];
        if (L > 0) {
            int g = 0;
            if (lane == 0) g = atomicAdd(&gcnt[bb], L);
            g = __shfl(g, 0, 64);
            if (lane < L && g + lane < CAPC)
                binned[(size_t)bb * CAPC + g + lane] = ring[bb * RCAP + lane];
        }
    }
}

// ------- exclusive scan of per-bucket totals -> bucketBase; rowptr[NN]=total -------
__global__ __launch_bounds__(128) void k_bases(const int* __restrict__ gcnt,
                                               int* __restrict__ bucketBase,
                                               int* __restrict__ rowptr) {
    __shared__ int part[128];
    int t = threadIdx.x;
    int T = 0;
    if (t < NBC) { T = gcnt[t]; if (T > CAPC) T = CAPC; }
    part[t] = T;
    __syncthreads();
    for (int off = 1; off < 128; off <<= 1) {
        int v = (t >= off) ? part[t - off] : 0;
        __syncthreads();
        part[t] += v;
        __syncthreads();
    }
    if (t < NBC) bucketBase[t] = part[t] - T;
    if (t == NBC - 1) { bucketBase[NBC] = part[t]; rowptr[NN] = part[t]; }
}

// ------- per-bucket two-pass: hist+deg, 1024-scan, scatter -> csr/rowptr/dinv -------
__global__ __launch_bounds__(256) void k_build(const int* __restrict__ gcnt,
                                               const long long* __restrict__ binned,
                                               const int* __restrict__ bucketBase,
                                               int2* __restrict__ csr,
                                               int* __restrict__ rowptr,
                                               float* __restrict__ dinv) {
    __shared__ int hist[NPBC];
    __shared__ int scn[NPBC];
    __shared__ float degs[NPBC];
    __shared__ int wsum[256];
    int b = blockIdx.x, t = threadIdx.x;
    int node0 = b * NPBC;
    int nloc = NN - node0; if (nloc > NPBC) nloc = NPBC;
    for (int i = t; i < NPBC; i += 256) { hist[i] = 0; degs[i] = 0.0f; }
    __syncthreads();
    int T = gcnt[b]; if (T > CAPC) T = CAPC;
    const long long* bp = binned + (size_t)b * CAPC;
    for (int i = t; i < T; i += 256) {
        long long v = nt_ll(bp + i);
        int dlow = (((unsigned)(int)v) >> 17) & 1023;
        atomicAdd(&hist[dlow], 1);
        atomicAdd(&degs[dlow], __int_as_float((int)(v >> 32)));
    }
    __syncthreads();
    // hierarchical exclusive scan of hist[1024]: 4 per thread
    int s0 = hist[t * 4], s1 = hist[t * 4 + 1], s2 = hist[t * 4 + 2], s3 = hist[t * 4 + 3];
    wsum[t] = s0 + s1 + s2 + s3;
    __syncthreads();
    for (int off = 1; off < 256; off <<= 1) {
        int v = (t >= off) ? wsum[t - off] : 0;
        __syncthreads();
        wsum[t] += v;
        __syncthreads();
    }
    int ebase = (t > 0) ? wsum[t - 1] : 0;
    scn[t * 4] = ebase;
    scn[t * 4 + 1] = ebase + s0;
    scn[t * 4 + 2] = ebase + s0 + s1;
    scn[t * 4 + 3] = ebase + s0 + s1 + s2;
    __syncthreads();
    int base = bucketBase[b];
    for (int i = t; i < nloc; i += 256) {
        rowptr[node0 + i] = base + scn[i];
        dinv[node0 + i] = 1.0f / sqrtf(1.0f + degs[i]);   // +1 = self-loop weight
    }
    for (int i = t; i < NPBC; i += 256) hist[i] = scn[i]; // hist becomes fill cursor
    __syncthreads();
    for (int i = t; i < T; i += 256) {
        long long v = nt_ll(bp + i);
        int xi = (int)v;
        int dlow = (((unsigned)xi) >> 17) & 1023;
        int slot = atomicAdd(&hist[dlow], 1);
        int2 ent;
        ent.x = xi & 0x1FFFF;
        ent.y = (int)(v >> 32);
        csr[(size_t)base + slot] = ent;                   // scatter within ~262KB window
    }
}

// ---------------- norm: csr.y := dinv[src]*w*dinv[dst] (in place, once) ---------------
__global__ __launch_bounds__(256) void k_norm(const int* __restrict__ rowptr,
                                              int2* __restrict__ csr,
                                              const float* __restrict__ dinv, int n) {
    int t = threadIdx.x, wv = t >> 6, lane = t & 63;
    int node = blockIdx.x * 4 + wv;
    if (node >= n) return;
    float di = dinv[node];
    int lo = rowptr[node], hi = rowptr[node + 1];
    for (int j = lo + lane; j < hi; j += 64) {
        int2 e = csr[j];
        e.y = __float_as_int(dinv[e.x] * __int_as_float(e.y) * di);
        csr[j] = e;
    }
}

// ---- propagate 32-ch input x (precomputed norm): wave per node, 2 edges x 32 ch ----
__global__ __launch_bounds__(256) void k_prop1x(const float* __restrict__ x,
                                                const int* __restrict__ rowptr,
                                                const int2* __restrict__ csr,
                                                const float* __restrict__ dinv,
                                                float* __restrict__ out, int n) {
    int t = threadIdx.x, wv = t >> 6, lane = t & 63;
    int ep = lane >> 5, ch = lane & 31;
    int node = blockIdx.x * 4 + wv;
    if (node >= n) return;
    float di = dinv[node];
    int lo = rowptr[node], hi = rowptr[node + 1];
    float acc = 0.0f;
    int j = lo + ep;
    for (; j + 2 < hi; j += 4) {               // 2 edges per half, 2-deep
        int2 e0 = csr[j], e1 = csr[j + 2];
        float g0 = x[(size_t)e0.x * 32 + ch];
        float g1 = x[(size_t)e1.x * 32 + ch];
        acc = fmaf(__int_as_float(e0.y), g0, acc);
        acc = fmaf(__int_as_float(e1.y), g1, acc);
    }
    if (j < hi) {
        int2 e = csr[j];
        acc = fmaf(__int_as_float(e.y), x[(size_t)e.x * 32 + ch], acc);
    }
    acc += __shfl_xor(acc, 32);                // merge the two edge-halves
    if (ep == 0) {
        acc += di * di * x[(size_t)node * 32 + ch];
        out[(size_t)node * 32 + ch] = acc;
    }
}

// ---------------- GEMM: out[n][64] = h[n][FIN] @ W[FIN][64] (+bias/relu opt) ----
template<int FIN>
__global__ __launch_bounds__(256) void k_gemm(const float* __restrict__ h,
                                              const float* __restrict__ W,
                                              const float* __restrict__ bias,
                                              float* __restrict__ out, int n, int relu) {
    __shared__ float Wl[FIN * 64];
    int t = threadIdx.x;
    for (int i = t; i < FIN * 64; i += 256) Wl[i] = W[i];
    __syncthreads();
    int lane = t & 63, wv = t >> 6;
    float wc[FIN];
#pragma unroll
    for (int k = 0; k < FIN; ++k) wc[k] = Wl[k * 64 + lane];
    float bs = bias ? bias[lane] : 0.0f;
    int base = blockIdx.x * 32 + wv * 8;
#pragma unroll 1
    for (int nd = base; nd < base + 8; ++nd) {
        if (nd >= n) break;
        const float4* row4 = (const float4*)(h + (size_t)nd * FIN);
        float acc = 0.0f;
#pragma unroll
        for (int k4 = 0; k4 < FIN / 4; ++k4) {
            float4 v = row4[k4];
            acc = fmaf(v.x, wc[4 * k4 + 0], acc);
            acc = fmaf(v.y, wc[4 * k4 + 1], acc);
            acc = fmaf(v.z, wc[4 * k4 + 2], acc);
            acc = fmaf(v.w, wc[4 * k4 + 3], acc);
        }
        acc += bs;
        if (relu) acc = fmaxf(acc, 0.0f);
        out[(size_t)nd * 64 + lane] = acc;
    }
}

// -- propagate 64ch (precomputed norm): out = di^2*hw[n] + sum nm*hw[s] + b --
__global__ __launch_bounds__(256) void k_prop(const float* __restrict__ hw,
                                              const int* __restrict__ rowptr,
                                              const int2* __restrict__ csr,
                                              const float* __restrict__ dinv,
                                              const float* __restrict__ bias,
                                              float* __restrict__ out, int n, int relu) {
    int t = threadIdx.x;
    int lane = t & 63, wv = t >> 6;
    int node = blockIdx.x * 4 + wv;
    if (node >= n) return;
    float di = dinv[node];
    float acc = di * di * hw[(size_t)node * 64 + lane];
    int lo = rowptr[node], hi = rowptr[node + 1];
    int j = lo;
    for (; j + 7 < hi; j += 8) {               // 8 gathers in flight
        int2 e0 = csr[j],     e1 = csr[j + 1], e2 = csr[j + 2], e3 = csr[j + 3];
        int2 e4 = csr[j + 4], e5 = csr[j + 5], e6 = csr[j + 6], e7 = csr[j + 7];
        float g0 = hw[(size_t)e0.x * 64 + lane];
        float g1 = hw[(size_t)e1.x * 64 + lane];
        float g2 = hw[(size_t)e2.x * 64 + lane];
        float g3 = hw[(size_t)e3.x * 64 + lane];
        float g4 = hw[(size_t)e4.x * 64 + lane];
        float g5 = hw[(size_t)e5.x * 64 + lane];
        float g6 = hw[(size_t)e6.x * 64 + lane];
        float g7 = hw[(size_t)e7.x * 64 + lane];
        acc = fmaf(__int_as_float(e0.y), g0, acc);
        acc = fmaf(__int_as_float(e1.y), g1, acc);
        acc = fmaf(__int_as_float(e2.y), g2, acc);
        acc = fmaf(__int_as_float(e3.y), g3, acc);
        acc = fmaf(__int_as_float(e4.y), g4, acc);
        acc = fmaf(__int_as_float(e5.y), g5, acc);
        acc = fmaf(__int_as_float(e6.y), g6, acc);
        acc = fmaf(__int_as_float(e7.y), g7, acc);
    }
    for (; j < hi; ++j) {
        int2 e = csr[j];
        acc = fmaf(__int_as_float(e.y), hw[(size_t)e.x * 64 + lane], acc);
    }
    acc += bias[lane];
    if (relu) acc = fmaxf(acc, 0.0f);
    out[(size_t)node * 64 + lane] = acc;
}

// ------- decoder: 4 labels per wave, gathers issued upfront, reductions interleaved -------
__global__ __launch_bounds__(256) void k_decode(const float* __restrict__ z,
                                                const int* __restrict__ eli,
                                                float* __restrict__ out, int L) {
    __shared__ float res[16];
    int t = threadIdx.x, wv = t >> 6, lane = t & 63;
    int base = blockIdx.x * 16;
    int l0 = base + wv * 4;
    float p0 = 0.0f, p1 = 0.0f, p2 = 0.0f, p3 = 0.0f;
    if (l0 + 0 < L) {
        int a = __builtin_nontemporal_load(eli + l0);
        int b = __builtin_nontemporal_load(eli + L + l0);
        p0 = z[(size_t)a * 64 + lane] * z[(size_t)b * 64 + lane];
    }
    if (l0 + 1 < L) {
        int a = __builtin_nontemporal_load(eli + l0 + 1);
        int b = __builtin_nontemporal_load(eli + L + l0 + 1);
        p1 = z[(size_t)a * 64 + lane] * z[(size_t)b * 64 + lane];
    }
    if (l0 + 2 < L) {
        int a = __builtin_nontemporal_load(eli + l0 + 2);
        int b = __builtin_nontemporal_load(eli + L + l0 + 2);
        p2 = z[(size_t)a * 64 + lane] * z[(size_t)b * 64 + lane];
    }
    if (l0 + 3 < L) {
        int a = __builtin_nontemporal_load(eli + l0 + 3);
        int b = __builtin_nontemporal_load(eli + L + l0 + 3);
        p3 = z[(size_t)a * 64 + lane] * z[(size_t)b * 64 + lane];
    }
#pragma unroll
    for (int o = 32; o > 0; o >>= 1) {
        p0 += __shfl_xor(p0, o, 64);
        p1 += __shfl_xor(p1, o, 64);
        p2 += __shfl_xor(p2, o, 64);
        p3 += __shfl_xor(p3, o, 64);
    }
    if (lane == 0) {
        res[wv * 4 + 0] = p0; res[wv * 4 + 1] = p1;
        res[wv * 4 + 2] = p2; res[wv * 4 + 3] = p3;
    }
    __syncthreads();
    if (t < 16 && base + t < L) out[base + t] = res[t];
}

extern "C" void kernel_launch(void* const* d_in, const int* in_sizes, int n_in,
                              void* d_out, int out_size, void* d_ws, size_t ws_size,
                              hipStream_t stream) {
    const float* x   = (const float*)d_in[0];        // [NN, 32]
    const float* ew  = (const float*)d_in[1];        // [NE]
    const int*   ei  = (const int*)d_in[2];          // [2, NE]
    const int*   eli = (const int*)d_in[3];          // [2, NL]
    const float* W1 = (const float*)d_in[4];  const float* b1 = (const float*)d_in[5];
    const float* W2 = (const float*)d_in[6];  const float* b2 = (const float*)d_in[7];
    const float* W3 = (const float*)d_in[8];  const float* b3 = (const float*)d_in[9];
    const float* W4 = (const float*)d_in[10]; const float* b4 = (const float*)d_in[11];
    const float* W5 = (const float*)d_in[12]; const float* b5 = (const float*)d_in[13];
    float* out = (float*)d_out;

    const int* src = ei;
    const int* dst = ei + NE;

    // ---- carve workspace (256B aligned) ----
    char* w = (char*)d_ws;
    size_t off = 0;
    auto carve = [&](size_t bytes) -> void* {
        void* p = w + off;
        off = (off + bytes + 255) & ~(size_t)255;
        return p;
    };
    float*     dinv   = (float*)carve(sizeof(float) * NN);
    int*       gcnt   = (int*)  carve(sizeof(int) * NBC);
    int*       rowptr = (int*)  carve(sizeof(int) * (NN + 1));
    int*       bbase  = (int*)  carve(sizeof(int) * (NBC + 1));
    int2*      csr    = (int2*) carve(sizeof(int2) * NE);
    // binned (27.3MB) aliases bufA (25.6MB): binned is dead before bufA's
    // first write (k_prop1x runs after k_build's last binned read).
    long long* binned = (long long*)carve(sizeof(long long) * (size_t)NBC * CAPC);
    float*     bufA   = (float*)binned;
    float*     bufB   = (float*)carve(sizeof(float) * (size_t)NN * 64);
    (void)ws_size; (void)n_in; (void)in_sizes; (void)out_size;

    const int TB = 256;
    int gW4 = (NN + 3) / 4;       // 4 nodes/block (wave per node)
    int gG  = (NN + 31) / 32;     // gemm: 32 nodes/block
    int gD  = (NL + 15) / 16;     // decode: 16 labels/block

    // ---- graph preprocessing: coarse partition -> CSR + dinv + norm ----
    const int BINB = 512;
    int epb = (NE + BINB - 1) / BINB;
    k_zero <<<1, 128, 0, stream>>>(gcnt, NBC);
    k_bin  <<<BINB, TB, 0, stream>>>(src, dst, ew, gcnt, binned, NE, epb);
    k_bases<<<1, 128, 0, stream>>>(gcnt, bbase, rowptr);
    k_build<<<NBC, TB, 0, stream>>>(gcnt, binned, bbase, csr, rowptr, dinv);
    k_norm <<<gW4, TB, 0, stream>>>(rowptr, csr, dinv, NN);

    // ---- layer 1: (A x) @ W1 + b1, relu ----
    k_prop1x<<<gW4, TB, 0, stream>>>(x, rowptr, csr, dinv, bufA, NN);
    k_gemm<32><<<gG, TB, 0, stream>>>(bufA, W1, b1, bufB, NN, 1);
    // ---- layers 2..4 ----
    k_gemm<64><<<gG, TB, 0, stream>>>(bufB, W2, nullptr, bufA, NN, 0);
    k_prop<<<gW4, TB, 0, stream>>>(bufA, rowptr, csr, dinv, b2, bufB, NN, 1);
    k_gemm<64><<<gG, TB, 0, stream>>>(bufB, W3, nullptr, bufA, NN, 0);
    k_prop<<<gW4, TB, 0, stream>>>(bufA, rowptr, csr, dinv, b3, bufB, NN, 1);
    k_gemm<64><<<gG, TB, 0, stream>>>(bufB, W4, nullptr, bufA, NN, 0);
    k_prop<<<gW4, TB, 0, stream>>>(bufA, rowptr, csr, dinv, b4, bufB, NN, 1);
    // ---- layer 5 (no relu) ----
    k_gemm<64><<<gG, TB, 0, stream>>>(bufB, W5, nullptr, bufA, NN, 0);
    k_prop<<<gW4, TB, 0, stream>>>(bufA, rowptr, csr, dinv, b5, bufB, NN, 0);

    // ---- decode ----
    k_decode<<<gD, TB, 0, stream>>>(bufB, eli, out, NL);
}

// Round 14
// 1189.461 us; speedup vs baseline: 1.3029x; 1.3029x over previous
//
#include <hip/hip_runtime.h>
#include <hip/hip_bf16.h>

#define NN 100000
#define NE 3200000
#define NL 1000000
#define NBC 98                          // coarse buckets (dst >> 10)
#define NPBC 1024                       // nodes per coarse bucket
#define CAPC 34816                      // per-bucket capacity (mean 32768, +11 sigma)
#define EPB 4096                        // edges per k_bin block

__device__ __forceinline__ long long nt_ll(const void* p) {
    return __builtin_nontemporal_load((const long long*)p);
}

// ---------------- zero int buffer ----------------
__global__ void k_zero(int* __restrict__ p, int n) {
    int i = blockIdx.x * blockDim.x + threadIdx.x;
    if (i < n) p[i] = 0;
}

// ------- block-local counting sort: 4096 edges -> 98 bucket runs, coalesced out -------
__global__ __launch_bounds__(256) void k_bin(const int* __restrict__ src,
                                             const int* __restrict__ dst,
                                             const float* __restrict__ w,
                                             int* __restrict__ gcnt,
                                             long long* __restrict__ binned,
                                             int e_cnt) {
    __shared__ long long sorted[EPB];          // 32 KB
    __shared__ unsigned char bkt[EPB];         // 4 KB
    __shared__ int hist[NBC], scn[NBC], cur[NBC], gbase[NBC];
    __shared__ int part[128];
    int t = threadIdx.x;
    int e0 = blockIdx.x * EPB;
    int cnt = e_cnt - e0; if (cnt > EPB) cnt = EPB;

    for (int i = t; i < NBC; i += 256) hist[i] = 0;
    __syncthreads();
    // pass 1: bucket histogram (dst only)
    for (int i = t; i < cnt; i += 256) {
        int d = __builtin_nontemporal_load(dst + e0 + i);
        atomicAdd(&hist[d >> 10], 1);
    }
    __syncthreads();
    // exclusive scan over 98 buckets (128-thread Hillis-Steele)
    if (t < 128) part[t] = (t < NBC) ? hist[t] : 0;
    __syncthreads();
    for (int o = 1; o < 128; o <<= 1) {
        int v = 0;
        if (t < 128 && t >= o) v = part[t - o];
        __syncthreads();
        if (t < 128) part[t] += v;
        __syncthreads();
    }
    if (t < NBC) {
        int ex = part[t] - hist[t];
        scn[t] = ex;
        cur[t] = ex;
        gbase[t] = atomicAdd(&gcnt[t], hist[t]);   // reserve global run
    }
    __syncthreads();
    // pass 2: scatter into sorted LDS order
    for (int i = t; i < cnt; i += 256) {
        int d = __builtin_nontemporal_load(dst + e0 + i);
        int s = __builtin_nontemporal_load(src + e0 + i);
        float wf = __builtin_nontemporal_load(w + e0 + i);
        int b = d >> 10;
        long long ent = (unsigned int)(s | ((d & 1023) << 17)) |
                        ((long long)__float_as_int(wf) << 32);
        int r = atomicAdd(&cur[b], 1);
        sorted[r] = ent;
        bkt[r] = (unsigned char)b;
    }
    __syncthreads();
    // pass 3: coalesced write of each bucket run
    for (int i = t; i < cnt; i += 256) {
        int b = bkt[i];
        int g = gbase[b] + (i - scn[b]);
        if (g < CAPC) binned[(size_t)b * CAPC + g] = sorted[i];
    }
}

// ------- exclusive scan of per-bucket totals -> bucketBase; rowptr[NN]=total -------
__global__ __launch_bounds__(128) void k_bases(const int* __restrict__ gcnt,
                                               int* __restrict__ bucketBase,
                                               int* __restrict__ rowptr) {
    __shared__ int part[128];
    int t = threadIdx.x;
    int T = 0;
    if (t < NBC) { T = gcnt[t]; if (T > CAPC) T = CAPC; }
    part[t] = T;
    __syncthreads();
    for (int off = 1; off < 128; off <<= 1) {
        int v = (t >= off) ? part[t - off] : 0;
        __syncthreads();
        part[t] += v;
        __syncthreads();
    }
    if (t < NBC) bucketBase[t] = part[t] - T;
    if (t == NBC - 1) { bucketBase[NBC] = part[t]; rowptr[NN] = part[t]; }
}

// ------- per-bucket two-pass: hist+deg, 1024-scan, scatter -> csr/rowptr/dinv -------
__global__ __launch_bounds__(256) void k_build(const int* __restrict__ gcnt,
                                               const long long* __restrict__ binned,
                                               const int* __restrict__ bucketBase,
                                               int2* __restrict__ csr,
                                               int* __restrict__ rowptr,
                                               float* __restrict__ dinv) {
    __shared__ int hist[NPBC];
    __shared__ int scn[NPBC];
    __shared__ float degs[NPBC];
    __shared__ int wsum[256];
    int b = blockIdx.x, t = threadIdx.x;
    int node0 = b * NPBC;
    int nloc = NN - node0; if (nloc > NPBC) nloc = NPBC;
    for (int i = t; i < NPBC; i += 256) { hist[i] = 0; degs[i] = 0.0f; }
    __syncthreads();
    int T = gcnt[b]; if (T > CAPC) T = CAPC;
    const long long* bp = binned + (size_t)b * CAPC;
    for (int i = t; i < T; i += 256) {
        long long v = nt_ll(bp + i);
        int dlow = (((unsigned)(int)v) >> 17) & 1023;
        atomicAdd(&hist[dlow], 1);
        atomicAdd(&degs[dlow], __int_as_float((int)(v >> 32)));
    }
    __syncthreads();
    // hierarchical exclusive scan of hist[1024]: 4 per thread
    int s0 = hist[t * 4], s1 = hist[t * 4 + 1], s2 = hist[t * 4 + 2], s3 = hist[t * 4 + 3];
    wsum[t] = s0 + s1 + s2 + s3;
    __syncthreads();
    for (int off = 1; off < 256; off <<= 1) {
        int v = (t >= off) ? wsum[t - off] : 0;
        __syncthreads();
        wsum[t] += v;
        __syncthreads();
    }
    int ebase = (t > 0) ? wsum[t - 1] : 0;
    scn[t * 4] = ebase;
    scn[t * 4 + 1] = ebase + s0;
    scn[t * 4 + 2] = ebase + s0 + s1;
    scn[t * 4 + 3] = ebase + s0 + s1 + s2;
    __syncthreads();
    int base = bucketBase[b];
    for (int i = t; i < nloc; i += 256) {
        rowptr[node0 + i] = base + scn[i];
        dinv[node0 + i] = 1.0f / sqrtf(1.0f + degs[i]);   // +1 = self-loop weight
    }
    for (int i = t; i < NPBC; i += 256) hist[i] = scn[i]; // hist becomes fill cursor
    __syncthreads();
    for (int i = t; i < T; i += 256) {
        long long v = nt_ll(bp + i);
        int xi = (int)v;
        int dlow = (((unsigned)xi) >> 17) & 1023;
        int slot = atomicAdd(&hist[dlow], 1);
        int2 ent;
        ent.x = xi & 0x1FFFF;
        ent.y = (int)(v >> 32);
        csr[(size_t)base + slot] = ent;                   // scatter within ~262KB window
    }
}

// ---------------- norm: csr.y := dinv[src]*w*dinv[dst] (in place, once) ---------------
__global__ __launch_bounds__(256) void k_norm(const int* __restrict__ rowptr,
                                              int2* __restrict__ csr,
                                              const float* __restrict__ dinv, int n) {
    int t = threadIdx.x, wv = t >> 6, lane = t & 63;
    int node = blockIdx.x * 4 + wv;
    if (node >= n) return;
    float di = dinv[node];
    int lo = rowptr[node], hi = rowptr[node + 1];
    for (int j = lo + lane; j < hi; j += 64) {
        int2 e = csr[j];
        e.y = __float_as_int(dinv[e.x] * __int_as_float(e.y) * di);
        csr[j] = e;
    }
}

// ---- propagate 32-ch input x (precomputed norm): wave per node, 2 edges x 32 ch ----
__global__ __launch_bounds__(256) void k_prop1x(const float* __restrict__ x,
                                                const int* __restrict__ rowptr,
                                                const int2* __restrict__ csr,
                                                const float* __restrict__ dinv,
                                                float* __restrict__ out, int n) {
    int t = threadIdx.x, wv = t >> 6, lane = t & 63;
    int ep = lane >> 5, ch = lane & 31;
    int node = blockIdx.x * 4 + wv;
    if (node >= n) return;
    float di = dinv[node];
    int lo = rowptr[node], hi = rowptr[node + 1];
    float acc = 0.0f;
    int j = lo + ep;
    for (; j + 2 < hi; j += 4) {               // 2 edges per half, 2-deep
        int2 e0 = csr[j], e1 = csr[j + 2];
        float g0 = x[(size_t)e0.x * 32 + ch];
        float g1 = x[(size_t)e1.x * 32 + ch];
        acc = fmaf(__int_as_float(e0.y), g0, acc);
        acc = fmaf(__int_as_float(e1.y), g1, acc);
    }
    if (j < hi) {
        int2 e = csr[j];
        acc = fmaf(__int_as_float(e.y), x[(size_t)e.x * 32 + ch], acc);
    }
    acc += __shfl_xor(acc, 32);                // merge the two edge-halves
    if (ep == 0) {
        acc += di * di * x[(size_t)node * 32 + ch];
        out[(size_t)node * 32 + ch] = acc;
    }
}

// ---------------- GEMM: out[n][64] = h[n][FIN] @ W[FIN][64] (+bias/relu opt) ----
template<int FIN>
__global__ __launch_bounds__(256) void k_gemm(const float* __restrict__ h,
                                              const float* __restrict__ W,
                                              const float* __restrict__ bias,
                                              float* __restrict__ out, int n, int relu) {
    __shared__ float Wl[FIN * 64];
    int t = threadIdx.x;
    for (int i = t; i < FIN * 64; i += 256) Wl[i] = W[i];
    __syncthreads();
    int lane = t & 63, wv = t >> 6;
    float wc[FIN];
#pragma unroll
    for (int k = 0; k < FIN; ++k) wc[k] = Wl[k * 64 + lane];
    float bs = bias ? bias[lane] : 0.0f;
    int base = blockIdx.x * 32 + wv * 8;
#pragma unroll 1
    for (int nd = base; nd < base + 8; ++nd) {
        if (nd >= n) break;
        const float4* row4 = (const float4*)(h + (size_t)nd * FIN);
        float acc = 0.0f;
#pragma unroll
        for (int k4 = 0; k4 < FIN / 4; ++k4) {
            float4 v = row4[k4];
            acc = fmaf(v.x, wc[4 * k4 + 0], acc);
            acc = fmaf(v.y, wc[4 * k4 + 1], acc);
            acc = fmaf(v.z, wc[4 * k4 + 2], acc);
            acc = fmaf(v.w, wc[4 * k4 + 3], acc);
        }
        acc += bs;
        if (relu) acc = fmaxf(acc, 0.0f);
        out[(size_t)nd * 64 + lane] = acc;
    }
}

// -- propagate 64ch (precomputed norm): out = di^2*hw[n] + sum nm*hw[s] + b --
__global__ __launch_bounds__(256) void k_prop(const float* __restrict__ hw,
                                              const int* __restrict__ rowptr,
                                              const int2* __restrict__ csr,
                                              const float* __restrict__ dinv,
                                              const float* __restrict__ bias,
                                              float* __restrict__ out, int n, int relu) {
    int t = threadIdx.x;
    int lane = t & 63, wv = t >> 6;
    int node = blockIdx.x * 4 + wv;
    if (node >= n) return;
    float di = dinv[node];
    float acc = di * di * hw[(size_t)node * 64 + lane];
    int lo = rowptr[node], hi = rowptr[node + 1];
    int j = lo;
    for (; j + 7 < hi; j += 8) {               // 8 gathers in flight
        int2 e0 = csr[j],     e1 = csr[j + 1], e2 = csr[j + 2], e3 = csr[j + 3];
        int2 e4 = csr[j + 4], e5 = csr[j + 5], e6 = csr[j + 6], e7 = csr[j + 7];
        float g0 = hw[(size_t)e0.x * 64 + lane];
        float g1 = hw[(size_t)e1.x * 64 + lane];
        float g2 = hw[(size_t)e2.x * 64 + lane];
        float g3 = hw[(size_t)e3.x * 64 + lane];
        float g4 = hw[(size_t)e4.x * 64 + lane];
        float g5 = hw[(size_t)e5.x * 64 + lane];
        float g6 = hw[(size_t)e6.x * 64 + lane];
        float g7 = hw[(size_t)e7.x * 64 + lane];
        acc = fmaf(__int_as_float(e0.y), g0, acc);
        acc = fmaf(__int_as_float(e1.y), g1, acc);
        acc = fmaf(__int_as_float(e2.y), g2, acc);
        acc = fmaf(__int_as_float(e3.y), g3, acc);
        acc = fmaf(__int_as_float(e4.y), g4, acc);
        acc = fmaf(__int_as_float(e5.y), g5, acc);
        acc = fmaf(__int_as_float(e6.y), g6, acc);
        acc = fmaf(__int_as_float(e7.y), g7, acc);
    }
    for (; j < hi; ++j) {
        int2 e = csr[j];
        acc = fmaf(__int_as_float(e.y), hw[(size_t)e.x * 64 + lane], acc);
    }
    acc += bias[lane];
    if (relu) acc = fmaxf(acc, 0.0f);
    out[(size_t)node * 64 + lane] = acc;
}

// ------- decoder: 4 labels per wave, gathers issued upfront, reductions interleaved -------
__global__ __launch_bounds__(256) void k_decode(const float* __restrict__ z,
                                                const int* __restrict__ eli,
                                                float* __restrict__ out, int L) {
    __shared__ float res[16];
    int t = threadIdx.x, wv = t >> 6, lane = t & 63;
    int base = blockIdx.x * 16;
    int l0 = base + wv * 4;
    float p0 = 0.0f, p1 = 0.0f, p2 = 0.0f, p3 = 0.0f;
    if (l0 + 0 < L) {
        int a = __builtin_nontemporal_load(eli + l0);
        int b = __builtin_nontemporal_load(eli + L + l0);
        p0 = z[(size_t)a * 64 + lane] * z[(size_t)b * 64 + lane];
    }
    if (l0 + 1 < L) {
        int a = __builtin_nontemporal_load(eli + l0 + 1);
        int b = __builtin_nontemporal_load(eli + L + l0 + 1);
        p1 = z[(size_t)a * 64 + lane] * z[(size_t)b * 64 + lane];
    }
    if (l0 + 2 < L) {
        int a = __builtin_nontemporal_load(eli + l0 + 2);
        int b = __builtin_nontemporal_load(eli + L + l0 + 2);
        p2 = z[(size_t)a * 64 + lane] * z[(size_t)b * 64 + lane];
    }
    if (l0 + 3 < L) {
        int a = __builtin_nontemporal_load(eli + l0 + 3);
        int b = __builtin_nontemporal_load(eli + L + l0 + 3);
        p3 = z[(size_t)a * 64 + lane] * z[(size_t)b * 64 + lane];
    }
#pragma unroll
    for (int o = 32; o > 0; o >>= 1) {
        p0 += __shfl_xor(p0, o, 64);
        p1 += __shfl_xor(p1, o, 64);
        p2 += __shfl_xor(p2, o, 64);
        p3 += __shfl_xor(p3, o, 64);
    }
    if (lane == 0) {
        res[wv * 4 + 0] = p0; res[wv * 4 + 1] = p1;
        res[wv * 4 + 2] = p2; res[wv * 4 + 3] = p3;
    }
    __syncthreads();
    if (t < 16 && base + t < L) out[base + t] = res[t];
}

extern "C" void kernel_launch(void* const* d_in, const int* in_sizes, int n_in,
                              void* d_out, int out_size, void* d_ws, size_t ws_size,
                              hipStream_t stream) {
    const float* x   = (const float*)d_in[0];        // [NN, 32]
    const float* ew  = (const float*)d_in[1];        // [NE]
    const int*   ei  = (const int*)d_in[2];          // [2, NE]
    const int*   eli = (const int*)d_in[3];          // [2, NL]
    const float* W1 = (const float*)d_in[4];  const float* b1 = (const float*)d_in[5];
    const float* W2 = (const float*)d_in[6];  const float* b2 = (const float*)d_in[7];
    const float* W3 = (const float*)d_in[8];  const float* b3 = (const float*)d_in[9];
    const float* W4 = (const float*)d_in[10]; const float* b4 = (const float*)d_in[11];
    const float* W5 = (const float*)d_in[12]; const float* b5 = (const float*)d_in[13];
    float* out = (float*)d_out;

    const int* src = ei;
    const int* dst = ei + NE;

    // ---- carve workspace (256B aligned) ----
    char* w = (char*)d_ws;
    size_t off = 0;
    auto carve = [&](size_t bytes) -> void* {
        void* p = w + off;
        off = (off + bytes + 255) & ~(size_t)255;
        return p;
    };
    float*     dinv   = (float*)carve(sizeof(float) * NN);
    int*       gcnt   = (int*)  carve(sizeof(int) * NBC);
    int*       rowptr = (int*)  carve(sizeof(int) * (NN + 1));
    int*       bbase  = (int*)  carve(sizeof(int) * (NBC + 1));
    int2*      csr    = (int2*) carve(sizeof(int2) * NE);
    // binned (27.3MB) aliases bufA (25.6MB): binned is dead before bufA's
    // first write (k_prop1x runs after k_build's last binned read).
    long long* binned = (long long*)carve(sizeof(long long) * (size_t)NBC * CAPC);
    float*     bufA   = (float*)binned;
    float*     bufB   = (float*)carve(sizeof(float) * (size_t)NN * 64);
    (void)ws_size; (void)n_in; (void)in_sizes; (void)out_size;

    const int TB = 256;
    int gW4 = (NN + 3) / 4;       // 4 nodes/block (wave per node)
    int gG  = (NN + 31) / 32;     // gemm: 32 nodes/block
    int gD  = (NL + 15) / 16;     // decode: 16 labels/block
    int gB  = (NE + EPB - 1) / EPB;

    // ---- graph preprocessing: block counting sort -> CSR + dinv + norm ----
    k_zero <<<1, 128, 0, stream>>>(gcnt, NBC);
    k_bin  <<<gB, TB, 0, stream>>>(src, dst, ew, gcnt, binned, NE);
    k_bases<<<1, 128, 0, stream>>>(gcnt, bbase, rowptr);
    k_build<<<NBC, TB, 0, stream>>>(gcnt, binned, bbase, csr, rowptr, dinv);
    k_norm <<<gW4, TB, 0, stream>>>(rowptr, csr, dinv, NN);

    // ---- layer 1: (A x) @ W1 + b1, relu ----
    k_prop1x<<<gW4, TB, 0, stream>>>(x, rowptr, csr, dinv, bufA, NN);
    k_gemm<32><<<gG, TB, 0, stream>>>(bufA, W1, b1, bufB, NN, 1);
    // ---- layers 2..4 ----
    k_gemm<64><<<gG, TB, 0, stream>>>(bufB, W2, nullptr, bufA, NN, 0);
    k_prop<<<gW4, TB, 0, stream>>>(bufA, rowptr, csr, dinv, b2, bufB, NN, 1);
    k_gemm<64><<<gG, TB, 0, stream>>>(bufB, W3, nullptr, bufA, NN, 0);
    k_prop<<<gW4, TB, 0, stream>>>(bufA, rowptr, csr, dinv, b3, bufB, NN, 1);
    k_gemm<64><<<gG, TB, 0, stream>>>(bufB, W4, nullptr, bufA, NN, 0);
    k_prop<<<gW4, TB, 0, stream>>>(bufA, rowptr, csr, dinv, b4, bufB, NN, 1);
    // ---- layer 5 (no relu) ----
    k_gemm<64><<<gG, TB, 0, stream>>>(bufB, W5, nullptr, bufA, NN, 0);
    k_prop<<<gW4, TB, 0, stream>>>(bufA, rowptr, csr, dinv, b5, bufB, NN, 0);

    // ---- decode ----
    k_decode<<<gD, TB, 0, stream>>>(bufB, eli, out, NL);
}

// Round 15
// 1048.664 us; speedup vs baseline: 1.4778x; 1.1343x over previous
//
#include <hip/hip_runtime.h>
#include <hip/hip_bf16.h>

#define NN 100000
#define NE 3200000
#define NL 1000000
#define NBC 98                          // coarse buckets (dst >> 10)
#define NPBC 1024                       // nodes per coarse bucket
#define CAPC 34816                      // per-bucket capacity (mean 32768, +11 sigma)
#define EPB 4096                        // edges per k_bin block

__device__ __forceinline__ long long nt_ll(const void* p) {
    return __builtin_nontemporal_load((const long long*)p);
}

// ---------------- zero int buffer ----------------
__global__ void k_zero(int* __restrict__ p, int n) {
    int i = blockIdx.x * blockDim.x + threadIdx.x;
    if (i < n) p[i] = 0;
}

// ------- block-local counting sort: 4096 edges -> 98 bucket runs, coalesced out -------
__global__ __launch_bounds__(256) void k_bin(const int* __restrict__ src,
                                             const int* __restrict__ dst,
                                             const float* __restrict__ w,
                                             int* __restrict__ gcnt,
                                             long long* __restrict__ binned,
                                             int e_cnt) {
    __shared__ long long sorted[EPB];          // 32 KB
    __shared__ unsigned char bkt[EPB];         // 4 KB
    __shared__ int hist[NBC], scn[NBC], cur[NBC], gbase[NBC];
    __shared__ int part[128];
    int t = threadIdx.x;
    int e0 = blockIdx.x * EPB;
    int cnt = e_cnt - e0; if (cnt > EPB) cnt = EPB;

    for (int i = t; i < NBC; i += 256) hist[i] = 0;
    __syncthreads();
    // pass 1: bucket histogram (dst only)
    for (int i = t; i < cnt; i += 256) {
        int d = __builtin_nontemporal_load(dst + e0 + i);
        atomicAdd(&hist[d >> 10], 1);
    }
    __syncthreads();
    // exclusive scan over 98 buckets (128-thread Hillis-Steele)
    if (t < 128) part[t] = (t < NBC) ? hist[t] : 0;
    __syncthreads();
    for (int o = 1; o < 128; o <<= 1) {
        int v = 0;
        if (t < 128 && t >= o) v = part[t - o];
        __syncthreads();
        if (t < 128) part[t] += v;
        __syncthreads();
    }
    if (t < NBC) {
        int ex = part[t] - hist[t];
        scn[t] = ex;
        cur[t] = ex;
        gbase[t] = atomicAdd(&gcnt[t], hist[t]);   // reserve global run
    }
    __syncthreads();
    // pass 2: scatter into sorted LDS order
    for (int i = t; i < cnt; i += 256) {
        int d = __builtin_nontemporal_load(dst + e0 + i);
        int s = __builtin_nontemporal_load(src + e0 + i);
        float wf = __builtin_nontemporal_load(w + e0 + i);
        int b = d >> 10;
        long long ent = (unsigned int)(s | ((d & 1023) << 17)) |
                        ((long long)__float_as_int(wf) << 32);
        int r = atomicAdd(&cur[b], 1);
        sorted[r] = ent;
        bkt[r] = (unsigned char)b;
    }
    __syncthreads();
    // pass 3: coalesced write of each bucket run
    for (int i = t; i < cnt; i += 256) {
        int b = bkt[i];
        int g = gbase[b] + (i - scn[b]);
        if (g < CAPC) binned[(size_t)b * CAPC + g] = sorted[i];
    }
}

// ------- exclusive scan of per-bucket totals -> bucketBase; rowptr[NN]=total -------
__global__ __launch_bounds__(128) void k_bases(const int* __restrict__ gcnt,
                                               int* __restrict__ bucketBase,
                                               int* __restrict__ rowptr) {
    __shared__ int part[128];
    int t = threadIdx.x;
    int T = 0;
    if (t < NBC) { T = gcnt[t]; if (T > CAPC) T = CAPC; }
    part[t] = T;
    __syncthreads();
    for (int off = 1; off < 128; off <<= 1) {
        int v = (t >= off) ? part[t - off] : 0;
        __syncthreads();
        part[t] += v;
        __syncthreads();
    }
    if (t < NBC) bucketBase[t] = part[t] - T;
    if (t == NBC - 1) { bucketBase[NBC] = part[t]; rowptr[NN] = part[t]; }
}

// ------- per-bucket two-pass: hist+deg, 1024-scan, scatter -> csr/rowptr/dinv -------
__global__ __launch_bounds__(256) void k_build(const int* __restrict__ gcnt,
                                               const long long* __restrict__ binned,
                                               const int* __restrict__ bucketBase,
                                               int2* __restrict__ csr,
                                               int* __restrict__ rowptr,
                                               float* __restrict__ dinv) {
    __shared__ int hist[NPBC];
    __shared__ int scn[NPBC];
    __shared__ float degs[NPBC];
    __shared__ int wsum[256];
    int b = blockIdx.x, t = threadIdx.x;
    int node0 = b * NPBC;
    int nloc = NN - node0; if (nloc > NPBC) nloc = NPBC;
    for (int i = t; i < NPBC; i += 256) { hist[i] = 0; degs[i] = 0.0f; }
    __syncthreads();
    int T = gcnt[b]; if (T > CAPC) T = CAPC;
    const long long* bp = binned + (size_t)b * CAPC;
    for (int i = t; i < T; i += 256) {
        long long v = nt_ll(bp + i);
        int dlow = (((unsigned)(int)v) >> 17) & 1023;
        atomicAdd(&hist[dlow], 1);
        atomicAdd(&degs[dlow], __int_as_float((int)(v >> 32)));
    }
    __syncthreads();
    // hierarchical exclusive scan of hist[1024]: 4 per thread
    int s0 = hist[t * 4], s1 = hist[t * 4 + 1], s2 = hist[t * 4 + 2], s3 = hist[t * 4 + 3];
    wsum[t] = s0 + s1 + s2 + s3;
    __syncthreads();
    for (int off = 1; off < 256; off <<= 1) {
        int v = (t >= off) ? wsum[t - off] : 0;
        __syncthreads();
        wsum[t] += v;
        __syncthreads();
    }
    int ebase = (t > 0) ? wsum[t - 1] : 0;
    scn[t * 4] = ebase;
    scn[t * 4 + 1] = ebase + s0;
    scn[t * 4 + 2] = ebase + s0 + s1;
    scn[t * 4 + 3] = ebase + s0 + s1 + s2;
    __syncthreads();
    int base = bucketBase[b];
    for (int i = t; i < nloc; i += 256) {
        rowptr[node0 + i] = base + scn[i];
        dinv[node0 + i] = 1.0f / sqrtf(1.0f + degs[i]);   // +1 = self-loop weight
    }
    for (int i = t; i < NPBC; i += 256) hist[i] = scn[i]; // hist becomes fill cursor
    __syncthreads();
    for (int i = t; i < T; i += 256) {
        long long v = nt_ll(bp + i);
        int xi = (int)v;
        int dlow = (((unsigned)xi) >> 17) & 1023;
        int slot = atomicAdd(&hist[dlow], 1);
        int2 ent;
        ent.x = xi & 0x1FFFF;
        ent.y = (int)(v >> 32);
        csr[(size_t)base + slot] = ent;                   // scatter within ~262KB window
    }
}

// ---------------- norm: csr.y := dinv[src]*w*dinv[dst] (in place, once) ---------------
__global__ __launch_bounds__(256) void k_norm(const int* __restrict__ rowptr,
                                              int2* __restrict__ csr,
                                              const float* __restrict__ dinv, int n) {
    int t = threadIdx.x, wv = t >> 6, lane = t & 63;
    int node = blockIdx.x * 4 + wv;
    if (node >= n) return;
    float di = dinv[node];
    int lo = rowptr[node], hi = rowptr[node + 1];
    for (int j = lo + lane; j < hi; j += 64) {
        int2 e = csr[j];
        e.y = __float_as_int(dinv[e.x] * __int_as_float(e.y) * di);
        csr[j] = e;
    }
}

// ---- propagate 32-ch x: wave/node, 8 lane-groups x float4, 8 edges/iter ----
__global__ __launch_bounds__(256) void k_prop1x(const float* __restrict__ x,
                                                const int* __restrict__ rowptr,
                                                const int2* __restrict__ csr,
                                                const float* __restrict__ dinv,
                                                float* __restrict__ out, int n) {
    int t = threadIdx.x, wv = t >> 6, lane = t & 63;
    int g = lane >> 3, li = lane & 7;          // 8 groups x 8 lanes; 8*4=32 ch
    int node = blockIdx.x * 4 + wv;
    if (node >= n) return;
    float di = dinv[node];
    int lo = rowptr[node], hi = rowptr[node + 1];
    float4 acc = make_float4(0.f, 0.f, 0.f, 0.f);
    int j = lo + g;
    for (; j + 8 < hi; j += 16) {              // each group: 2 edges in flight
        int2 e0 = csr[j], e1 = csr[j + 8];
        float4 v0 = *(const float4*)(x + (size_t)e0.x * 32 + li * 4);
        float4 v1 = *(const float4*)(x + (size_t)e1.x * 32 + li * 4);
        float n0 = __int_as_float(e0.y), n1 = __int_as_float(e1.y);
        acc.x = fmaf(n0, v0.x, acc.x); acc.y = fmaf(n0, v0.y, acc.y);
        acc.z = fmaf(n0, v0.z, acc.z); acc.w = fmaf(n0, v0.w, acc.w);
        acc.x = fmaf(n1, v1.x, acc.x); acc.y = fmaf(n1, v1.y, acc.y);
        acc.z = fmaf(n1, v1.z, acc.z); acc.w = fmaf(n1, v1.w, acc.w);
    }
    if (j < hi) {
        int2 e = csr[j];
        float4 v = *(const float4*)(x + (size_t)e.x * 32 + li * 4);
        float nm = __int_as_float(e.y);
        acc.x = fmaf(nm, v.x, acc.x); acc.y = fmaf(nm, v.y, acc.y);
        acc.z = fmaf(nm, v.z, acc.z); acc.w = fmaf(nm, v.w, acc.w);
    }
#pragma unroll
    for (int m = 8; m < 64; m <<= 1) {
        acc.x += __shfl_xor(acc.x, m, 64);
        acc.y += __shfl_xor(acc.y, m, 64);
        acc.z += __shfl_xor(acc.z, m, 64);
        acc.w += __shfl_xor(acc.w, m, 64);
    }
    if (g == 0) {
        float4 sv = *(const float4*)(x + (size_t)node * 32 + li * 4);
        float s = di * di;
        acc.x = fmaf(s, sv.x, acc.x); acc.y = fmaf(s, sv.y, acc.y);
        acc.z = fmaf(s, sv.z, acc.z); acc.w = fmaf(s, sv.w, acc.w);
        *(float4*)(out + (size_t)node * 32 + li * 4) = acc;
    }
}

// ---------------- GEMM: out[n][64] = h[n][FIN] @ W[FIN][64] (+bias/relu opt) ----
template<int FIN>
__global__ __launch_bounds__(256) void k_gemm(const float* __restrict__ h,
                                              const float* __restrict__ W,
                                              const float* __restrict__ bias,
                                              float* __restrict__ out, int n, int relu) {
    __shared__ float Wl[FIN * 64];
    int t = threadIdx.x;
    for (int i = t; i < FIN * 64; i += 256) Wl[i] = W[i];
    __syncthreads();
    int lane = t & 63, wv = t >> 6;
    float wc[FIN];
#pragma unroll
    for (int k = 0; k < FIN; ++k) wc[k] = Wl[k * 64 + lane];
    float bs = bias ? bias[lane] : 0.0f;
    int base = blockIdx.x * 32 + wv * 8;
#pragma unroll 1
    for (int nd = base; nd < base + 8; ++nd) {
        if (nd >= n) break;
        const float4* row4 = (const float4*)(h + (size_t)nd * FIN);
        float acc = 0.0f;
#pragma unroll
        for (int k4 = 0; k4 < FIN / 4; ++k4) {
            float4 v = row4[k4];
            acc = fmaf(v.x, wc[4 * k4 + 0], acc);
            acc = fmaf(v.y, wc[4 * k4 + 1], acc);
            acc = fmaf(v.z, wc[4 * k4 + 2], acc);
            acc = fmaf(v.w, wc[4 * k4 + 3], acc);
        }
        acc += bs;
        if (relu) acc = fmaxf(acc, 0.0f);
        out[(size_t)nd * 64 + lane] = acc;
    }
}

// -- propagate 64ch: wave/node, 4 lane-groups x float4, 4 edges/iter, 2-deep --
__global__ __launch_bounds__(256) void k_prop(const float* __restrict__ hw,
                                              const int* __restrict__ rowptr,
                                              const int2* __restrict__ csr,
                                              const float* __restrict__ dinv,
                                              const float* __restrict__ bias,
                                              float* __restrict__ out, int n, int relu) {
    int t = threadIdx.x;
    int lane = t & 63, wv = t >> 6;
    int g = lane >> 4, li = lane & 15;         // 4 groups x 16 lanes; 16*4=64 ch
    int node = blockIdx.x * 4 + wv;
    if (node >= n) return;
    float di = dinv[node];
    int lo = rowptr[node], hi = rowptr[node + 1];
    float4 acc = make_float4(0.f, 0.f, 0.f, 0.f);
    int j = lo + g;
    for (; j + 4 < hi; j += 8) {               // each group: 2 edges in flight
        int2 e0 = csr[j], e1 = csr[j + 4];
        float4 v0 = *(const float4*)(hw + (size_t)e0.x * 64 + li * 4);
        float4 v1 = *(const float4*)(hw + (size_t)e1.x * 64 + li * 4);
        float n0 = __int_as_float(e0.y), n1 = __int_as_float(e1.y);
        acc.x = fmaf(n0, v0.x, acc.x); acc.y = fmaf(n0, v0.y, acc.y);
        acc.z = fmaf(n0, v0.z, acc.z); acc.w = fmaf(n0, v0.w, acc.w);
        acc.x = fmaf(n1, v1.x, acc.x); acc.y = fmaf(n1, v1.y, acc.y);
        acc.z = fmaf(n1, v1.z, acc.z); acc.w = fmaf(n1, v1.w, acc.w);
    }
    if (j < hi) {
        int2 e = csr[j];
        float4 v = *(const float4*)(hw + (size_t)e.x * 64 + li * 4);
        float nm = __int_as_float(e.y);
        acc.x = fmaf(nm, v.x, acc.x); acc.y = fmaf(nm, v.y, acc.y);
        acc.z = fmaf(nm, v.z, acc.z); acc.w = fmaf(nm, v.w, acc.w);
    }
#pragma unroll
    for (int m = 16; m < 64; m <<= 1) {
        acc.x += __shfl_xor(acc.x, m, 64);
        acc.y += __shfl_xor(acc.y, m, 64);
        acc.z += __shfl_xor(acc.z, m, 64);
        acc.w += __shfl_xor(acc.w, m, 64);
    }
    if (g == 0) {
        float4 sv = *(const float4*)(hw + (size_t)node * 64 + li * 4);
        float s = di * di;
        acc.x = fmaf(s, sv.x, acc.x); acc.y = fmaf(s, sv.y, acc.y);
        acc.z = fmaf(s, sv.z, acc.z); acc.w = fmaf(s, sv.w, acc.w);
        const float4 bv = *(const float4*)(bias + li * 4);
        acc.x += bv.x; acc.y += bv.y; acc.z += bv.z; acc.w += bv.w;
        if (relu) {
            acc.x = fmaxf(acc.x, 0.f); acc.y = fmaxf(acc.y, 0.f);
            acc.z = fmaxf(acc.z, 0.f); acc.w = fmaxf(acc.w, 0.f);
        }
        *(float4*)(out + (size_t)node * 64 + li * 4) = acc;
    }
}

// ------- decoder: 4 labels/wave/iter via 16-lane float4 groups; 64 labels/block -------
__global__ __launch_bounds__(256) void k_decode(const float* __restrict__ z,
                                                const int* __restrict__ eli,
                                                float* __restrict__ out, int L) {
    __shared__ float res[64];
    int t = threadIdx.x, wv = t >> 6, lane = t & 63;
    int g = lane >> 4, li = lane & 15;
    int base = blockIdx.x * 64;
#pragma unroll
    for (int it = 0; it < 4; ++it) {
        int l = base + wv * 16 + it * 4 + g;
        float p = 0.0f;
        if (l < L) {
            int a = __builtin_nontemporal_load(eli + l);
            int b = __builtin_nontemporal_load(eli + L + l);
            float4 va = *(const float4*)(z + (size_t)a * 64 + li * 4);
            float4 vb = *(const float4*)(z + (size_t)b * 64 + li * 4);
            p = va.x * vb.x;
            p = fmaf(va.y, vb.y, p);
            p = fmaf(va.z, vb.z, p);
            p = fmaf(va.w, vb.w, p);
        }
#pragma unroll
        for (int m = 1; m < 16; m <<= 1) p += __shfl_xor(p, m, 64);
        if (li == 0) res[wv * 16 + it * 4 + g] = p;
    }
    __syncthreads();
    if (t < 64 && base + t < L) out[base + t] = res[t];
}

extern "C" void kernel_launch(void* const* d_in, const int* in_sizes, int n_in,
                              void* d_out, int out_size, void* d_ws, size_t ws_size,
                              hipStream_t stream) {
    const float* x   = (const float*)d_in[0];        // [NN, 32]
    const float* ew  = (const float*)d_in[1];        // [NE]
    const int*   ei  = (const int*)d_in[2];          // [2, NE]
    const int*   eli = (const int*)d_in[3];          // [2, NL]
    const float* W1 = (const float*)d_in[4];  const float* b1 = (const float*)d_in[5];
    const float* W2 = (const float*)d_in[6];  const float* b2 = (const float*)d_in[7];
    const float* W3 = (const float*)d_in[8];  const float* b3 = (const float*)d_in[9];
    const float* W4 = (const float*)d_in[10]; const float* b4 = (const float*)d_in[11];
    const float* W5 = (const float*)d_in[12]; const float* b5 = (const float*)d_in[13];
    float* out = (float*)d_out;

    const int* src = ei;
    const int* dst = ei + NE;

    // ---- carve workspace (256B aligned) ----
    char* w = (char*)d_ws;
    size_t off = 0;
    auto carve = [&](size_t bytes) -> void* {
        void* p = w + off;
        off = (off + bytes + 255) & ~(size_t)255;
        return p;
    };
    float*     dinv   = (float*)carve(sizeof(float) * NN);
    int*       gcnt   = (int*)  carve(sizeof(int) * NBC);
    int*       rowptr = (int*)  carve(sizeof(int) * (NN + 1));
    int*       bbase  = (int*)  carve(sizeof(int) * (NBC + 1));
    int2*      csr    = (int2*) carve(sizeof(int2) * NE);
    // binned (27.3MB) aliases bufA (25.6MB): binned is dead before bufA's
    // first write (k_prop1x runs after k_build's last binned read).
    long long* binned = (long long*)carve(sizeof(long long) * (size_t)NBC * CAPC);
    float*     bufA   = (float*)binned;
    float*     bufB   = (float*)carve(sizeof(float) * (size_t)NN * 64);
    (void)ws_size; (void)n_in; (void)in_sizes; (void)out_size;

    const int TB = 256;
    int gW4 = (NN + 3) / 4;       // 4 nodes/block (wave per node)
    int gG  = (NN + 31) / 32;     // gemm: 32 nodes/block
    int gD  = (NL + 63) / 64;     // decode: 64 labels/block
    int gB  = (NE + EPB - 1) / EPB;

    // ---- graph preprocessing: block counting sort -> CSR + dinv + norm ----
    k_zero <<<1, 128, 0, stream>>>(gcnt, NBC);
    k_bin  <<<gB, TB, 0, stream>>>(src, dst, ew, gcnt, binned, NE);
    k_bases<<<1, 128, 0, stream>>>(gcnt, bbase, rowptr);
    k_build<<<NBC, TB, 0, stream>>>(gcnt, binned, bbase, csr, rowptr, dinv);
    k_norm <<<gW4, TB, 0, stream>>>(rowptr, csr, dinv, NN);

    // ---- layer 1: (A x) @ W1 + b1, relu ----
    k_prop1x<<<gW4, TB, 0, stream>>>(x, rowptr, csr, dinv, bufA, NN);
    k_gemm<32><<<gG, TB, 0, stream>>>(bufA, W1, b1, bufB, NN, 1);
    // ---- layers 2..4 ----
    k_gemm<64><<<gG, TB, 0, stream>>>(bufB, W2, nullptr, bufA, NN, 0);
    k_prop<<<gW4, TB, 0, stream>>>(bufA, rowptr, csr, dinv, b2, bufB, NN, 1);
    k_gemm<64><<<gG, TB, 0, stream>>>(bufB, W3, nullptr, bufA, NN, 0);
    k_prop<<<gW4, TB, 0, stream>>>(bufA, rowptr, csr, dinv, b3, bufB, NN, 1);
    k_gemm<64><<<gG, TB, 0, stream>>>(bufB, W4, nullptr, bufA, NN, 0);
    k_prop<<<gW4, TB, 0, stream>>>(bufA, rowptr, csr, dinv, b4, bufB, NN, 1);
    // ---- layer 5 (no relu) ----
    k_gemm<64><<<gG, TB, 0, stream>>>(bufB, W5, nullptr, bufA, NN, 0);
    k_prop<<<gW4, TB, 0, stream>>>(bufA, rowptr, csr, dinv, b5, bufB, NN, 0);

    // ---- decode ----
    k_decode<<<gD, TB, 0, stream>>>(bufB, eli, out, NL);
}

// Round 17
// 1013.815 us; speedup vs baseline: 1.5286x; 1.0344x over previous
//
#include <hip/hip_runtime.h>
#include <hip/hip_bf16.h>

#define NN 100000
#define NE 3200000
#define NL 1000000
#define NBC 391                         // buckets (dst >> 8)
#define NPBC 256                        // nodes per bucket
#define CAPC 9216                       // per-bucket capacity (mean 8184, +11 sigma)
#define EPB 4096                        // edges per k_bin block

__device__ __forceinline__ long long nt_ll(const void* p) {
    return __builtin_nontemporal_load((const long long*)p);
}

// ---------------- zero int buffer ----------------
__global__ void k_zero(int* __restrict__ p, int n) {
    int i = blockIdx.x * blockDim.x + threadIdx.x;
    if (i < n) p[i] = 0;
}

// ------- block-local counting sort: 4096 edges -> 391 bucket runs, coalesced out -------
__global__ __launch_bounds__(256) void k_bin(const int* __restrict__ src,
                                             const int* __restrict__ dst,
                                             const float* __restrict__ w,
                                             int* __restrict__ gcnt,
                                             long long* __restrict__ binned,
                                             int e_cnt) {
    __shared__ long long sorted[EPB];          // 32 KB
    __shared__ unsigned short bkt[EPB];        // 8 KB (bucket id up to 390)
    __shared__ int hist[NBC], scn[NBC], cur[NBC], gbase[NBC];   // 6.3 KB
    __shared__ int psum[256];
    int t = threadIdx.x;
    int e0 = blockIdx.x * EPB;
    int cnt = e_cnt - e0; if (cnt > EPB) cnt = EPB;

    for (int i = t; i < NBC; i += 256) hist[i] = 0;
    __syncthreads();
    // pass 1: bucket histogram (dst only)
    for (int i = t; i < cnt; i += 256) {
        int d = __builtin_nontemporal_load(dst + e0 + i);
        atomicAdd(&hist[d >> 8], 1);
    }
    __syncthreads();
    // exclusive scan over 391 buckets: thread t owns buckets 2t, 2t+1
    int b0 = 2 * t, b1 = 2 * t + 1;
    int h0 = (b0 < NBC) ? hist[b0] : 0;
    int h1 = (b1 < NBC) ? hist[b1] : 0;
    psum[t] = h0 + h1;
    __syncthreads();
    for (int o = 1; o < 256; o <<= 1) {
        int v = (t >= o) ? psum[t - o] : 0;
        __syncthreads();
        psum[t] += v;
        __syncthreads();
    }
    int eb = psum[t] - (h0 + h1);
    if (b0 < NBC) { scn[b0] = eb; cur[b0] = eb; gbase[b0] = atomicAdd(&gcnt[b0], h0); }
    if (b1 < NBC) { scn[b1] = eb + h0; cur[b1] = eb + h0; gbase[b1] = atomicAdd(&gcnt[b1], h1); }
    __syncthreads();
    // pass 2: scatter into sorted LDS order
    for (int i = t; i < cnt; i += 256) {
        int d = __builtin_nontemporal_load(dst + e0 + i);
        int s = __builtin_nontemporal_load(src + e0 + i);
        float wf = __builtin_nontemporal_load(w + e0 + i);
        int b = d >> 8;
        long long ent = (unsigned int)(s | ((d & 255) << 17)) |
                        ((long long)__float_as_int(wf) << 32);
        int r = atomicAdd(&cur[b], 1);
        sorted[r] = ent;
        bkt[r] = (unsigned short)b;
    }
    __syncthreads();
    // pass 3: coalesced write of each bucket run
    for (int i = t; i < cnt; i += 256) {
        int b = bkt[i];
        int g = gbase[b] + (i - scn[b]);
        if (g < CAPC) binned[(size_t)b * CAPC + g] = sorted[i];
    }
}

// ------- exclusive scan of per-bucket totals -> bucketBase; rowptr[NN]=total -------
__global__ __launch_bounds__(512) void k_bases(const int* __restrict__ gcnt,
                                               int* __restrict__ bucketBase,
                                               int* __restrict__ rowptr) {
    __shared__ int part[512];
    int t = threadIdx.x;
    int T = 0;
    if (t < NBC) { T = gcnt[t]; if (T > CAPC) T = CAPC; }
    part[t] = T;
    __syncthreads();
    for (int off = 1; off < 512; off <<= 1) {
        int v = (t >= off) ? part[t - off] : 0;
        __syncthreads();
        part[t] += v;
        __syncthreads();
    }
    if (t < NBC) bucketBase[t] = part[t] - T;
    if (t == NBC - 1) { bucketBase[NBC] = part[t]; rowptr[NN] = part[t]; }
}

// ------- per-bucket two-pass: hist+deg, 256-scan, scatter -> csr/rowptr/dinv -------
__global__ __launch_bounds__(256) void k_build(const int* __restrict__ gcnt,
                                               const long long* __restrict__ binned,
                                               const int* __restrict__ bucketBase,
                                               int2* __restrict__ csr,
                                               int* __restrict__ rowptr,
                                               float* __restrict__ dinv) {
    __shared__ int hist[NPBC];
    __shared__ int scn[NPBC];
    __shared__ float degs[NPBC];
    int b = blockIdx.x, t = threadIdx.x;
    int node0 = b * NPBC;
    int nloc = NN - node0; if (nloc > NPBC) nloc = NPBC;
    hist[t] = 0; degs[t] = 0.0f;
    __syncthreads();
    int T = gcnt[b]; if (T > CAPC) T = CAPC;
    const long long* bp = binned + (size_t)b * CAPC;
    for (int i = t; i < T; i += 256) {
        long long v = nt_ll(bp + i);
        int dlow = (((unsigned)(int)v) >> 17) & 255;
        atomicAdd(&hist[dlow], 1);
        atomicAdd(&degs[dlow], __int_as_float((int)(v >> 32)));
    }
    __syncthreads();
    int h = hist[t];
    scn[t] = h;
    __syncthreads();
    for (int off = 1; off < 256; off <<= 1) {
        int v = (t >= off) ? scn[t - off] : 0;
        __syncthreads();
        scn[t] += v;
        __syncthreads();
    }
    int ex = scn[t] - h;
    int base = bucketBase[b];
    if (t < nloc) {
        rowptr[node0 + t] = base + ex;
        dinv[node0 + t] = 1.0f / sqrtf(1.0f + degs[t]);   // +1 = self-loop weight
    }
    __syncthreads();
    hist[t] = ex;                                  // hist becomes fill cursor
    __syncthreads();
    for (int i = t; i < T; i += 256) {
        long long v = nt_ll(bp + i);
        int xi = (int)v;
        int dlow = (((unsigned)xi) >> 17) & 255;
        int slot = atomicAdd(&hist[dlow], 1);
        int2 ent;
        ent.x = xi & 0x1FFFF;
        ent.y = (int)(v >> 32);
        csr[(size_t)base + slot] = ent;            // scatter within ~66KB window
    }
}

// ---------------- norm: csr.y := dinv[src]*w*dinv[dst] (in place, once) ---------------
__global__ __launch_bounds__(256) void k_norm(const int* __restrict__ rowptr,
                                              int2* __restrict__ csr,
                                              const float* __restrict__ dinv, int n) {
    int t = threadIdx.x, wv = t >> 6, lane = t & 63;
    int node = blockIdx.x * 4 + wv;
    if (node >= n) return;
    float di = dinv[node];
    int lo = rowptr[node], hi = rowptr[node + 1];
    for (int j = lo + lane; j < hi; j += 64) {
        int2 e = csr[j];
        e.y = __float_as_int(dinv[e.x] * __int_as_float(e.y) * di);
        csr[j] = e;
    }
}

// ---- propagate 32-ch x: wave/node, 8 lane-groups x float4, 8 edges/iter ----
__global__ __launch_bounds__(256) void k_prop1x(const float* __restrict__ x,
                                                const int* __restrict__ rowptr,
                                                const int2* __restrict__ csr,
                                                const float* __restrict__ dinv,
                                                float* __restrict__ out, int n) {
    int t = threadIdx.x, wv = t >> 6, lane = t & 63;
    int g = lane >> 3, li = lane & 7;          // 8 groups x 8 lanes; 8*4=32 ch
    int node = blockIdx.x * 4 + wv;
    if (node >= n) return;
    float di = dinv[node];
    int lo = rowptr[node], hi = rowptr[node + 1];
    float4 acc = make_float4(0.f, 0.f, 0.f, 0.f);
    int j = lo + g;
    for (; j + 8 < hi; j += 16) {              // each group: 2 edges in flight
        int2 e0 = csr[j], e1 = csr[j + 8];
        float4 v0 = *(const float4*)(x + (size_t)e0.x * 32 + li * 4);
        float4 v1 = *(const float4*)(x + (size_t)e1.x * 32 + li * 4);
        float n0 = __int_as_float(e0.y), n1 = __int_as_float(e1.y);
        acc.x = fmaf(n0, v0.x, acc.x); acc.y = fmaf(n0, v0.y, acc.y);
        acc.z = fmaf(n0, v0.z, acc.z); acc.w = fmaf(n0, v0.w, acc.w);
        acc.x = fmaf(n1, v1.x, acc.x); acc.y = fmaf(n1, v1.y, acc.y);
        acc.z = fmaf(n1, v1.z, acc.z); acc.w = fmaf(n1, v1.w, acc.w);
    }
    if (j < hi) {
        int2 e = csr[j];
        float4 v = *(const float4*)(x + (size_t)e.x * 32 + li * 4);
        float nm = __int_as_float(e.y);
        acc.x = fmaf(nm, v.x, acc.x); acc.y = fmaf(nm, v.y, acc.y);
        acc.z = fmaf(nm, v.z, acc.z); acc.w = fmaf(nm, v.w, acc.w);
    }
#pragma unroll
    for (int m = 8; m < 64; m <<= 1) {
        acc.x += __shfl_xor(acc.x, m, 64);
        acc.y += __shfl_xor(acc.y, m, 64);
        acc.z += __shfl_xor(acc.z, m, 64);
        acc.w += __shfl_xor(acc.w, m, 64);
    }
    if (g == 0) {
        float4 sv = *(const float4*)(x + (size_t)node * 32 + li * 4);
        float s = di * di;
        acc.x = fmaf(s, sv.x, acc.x); acc.y = fmaf(s, sv.y, acc.y);
        acc.z = fmaf(s, sv.z, acc.z); acc.w = fmaf(s, sv.w, acc.w);
        *(float4*)(out + (size_t)node * 32 + li * 4) = acc;
    }
}

// ---------------- GEMM: out[n][64] = h[n][FIN] @ W[FIN][64] (+bias/relu opt) ----
template<int FIN>
__global__ __launch_bounds__(256) void k_gemm(const float* __restrict__ h,
                                              const float* __restrict__ W,
                                              const float* __restrict__ bias,
                                              float* __restrict__ out, int n, int relu) {
    __shared__ float Wl[FIN * 64];
    int t = threadIdx.x;
    for (int i = t; i < FIN * 64; i += 256) Wl[i] = W[i];
    __syncthreads();
    int lane = t & 63, wv = t >> 6;
    float wc[FIN];
#pragma unroll
    for (int k = 0; k < FIN; ++k) wc[k] = Wl[k * 64 + lane];
    float bs = bias ? bias[lane] : 0.0f;
    int base = blockIdx.x * 32 + wv * 8;
#pragma unroll 1
    for (int nd = base; nd < base + 8; ++nd) {
        if (nd >= n) break;
        const float4* row4 = (const float4*)(h + (size_t)nd * FIN);
        float acc = 0.0f;
#pragma unroll
        for (int k4 = 0; k4 < FIN / 4; ++k4) {
            float4 v = row4[k4];
            acc = fmaf(v.x, wc[4 * k4 + 0], acc);
            acc = fmaf(v.y, wc[4 * k4 + 1], acc);
            acc = fmaf(v.z, wc[4 * k4 + 2], acc);
            acc = fmaf(v.w, wc[4 * k4 + 3], acc);
        }
        acc += bs;
        if (relu) acc = fmaxf(acc, 0.0f);
        out[(size_t)nd * 64 + lane] = acc;
    }
}

// -- propagate 64ch: wave/node, 4 lane-groups x float4, 4 edges/iter, 2-deep --
__global__ __launch_bounds__(256) void k_prop(const float* __restrict__ hw,
                                              const int* __restrict__ rowptr,
                                              const int2* __restrict__ csr,
                                              const float* __restrict__ dinv,
                                              const float* __restrict__ bias,
                                              float* __restrict__ out, int n, int relu) {
    int t = threadIdx.x;
    int lane = t & 63, wv = t >> 6;
    int g = lane >> 4, li = lane & 15;         // 4 groups x 16 lanes; 16*4=64 ch
    int node = blockIdx.x * 4 + wv;
    if (node >= n) return;
    float di = dinv[node];
    int lo = rowptr[node], hi = rowptr[node + 1];
    float4 acc = make_float4(0.f, 0.f, 0.f, 0.f);
    int j = lo + g;
    for (; j + 4 < hi; j += 8) {               // each group: 2 edges in flight
        int2 e0 = csr[j], e1 = csr[j + 4];
        float4 v0 = *(const float4*)(hw + (size_t)e0.x * 64 + li * 4);
        float4 v1 = *(const float4*)(hw + (size_t)e1.x * 64 + li * 4);
        float n0 = __int_as_float(e0.y), n1 = __int_as_float(e1.y);
        acc.x = fmaf(n0, v0.x, acc.x); acc.y = fmaf(n0, v0.y, acc.y);
        acc.z = fmaf(n0, v0.z, acc.z); acc.w = fmaf(n0, v0.w, acc.w);
        acc.x = fmaf(n1, v1.x, acc.x); acc.y = fmaf(n1, v1.y, acc.y);
        acc.z = fmaf(n1, v1.z, acc.z); acc.w = fmaf(n1, v1.w, acc.w);
    }
    if (j < hi) {
        int2 e = csr[j];
        float4 v = *(const float4*)(hw + (size_t)e.x * 64 + li * 4);
        float nm = __int_as_float(e.y);
        acc.x = fmaf(nm, v.x, acc.x); acc.y = fmaf(nm, v.y, acc.y);
        acc.z = fmaf(nm, v.z, acc.z); acc.w = fmaf(nm, v.w, acc.w);
    }
#pragma unroll
    for (int m = 16; m < 64; m <<= 1) {
        acc.x += __shfl_xor(acc.x, m, 64);
        acc.y += __shfl_xor(acc.y, m, 64);
        acc.z += __shfl_xor(acc.z, m, 64);
        acc.w += __shfl_xor(acc.w, m, 64);
    }
    if (g == 0) {
        float4 sv = *(const float4*)(hw + (size_t)node * 64 + li * 4);
        float s = di * di;
        acc.x = fmaf(s, sv.x, acc.x); acc.y = fmaf(s, sv.y, acc.y);
        acc.z = fmaf(s, sv.z, acc.z); acc.w = fmaf(s, sv.w, acc.w);
        const float4 bv = *(const float4*)(bias + li * 4);
        acc.x += bv.x; acc.y += bv.y; acc.z += bv.z; acc.w += bv.w;
        if (relu) {
            acc.x = fmaxf(acc.x, 0.f); acc.y = fmaxf(acc.y, 0.f);
            acc.z = fmaxf(acc.z, 0.f); acc.w = fmaxf(acc.w, 0.f);
        }
        *(float4*)(out + (size_t)node * 64 + li * 4) = acc;
    }
}

// ------- decoder: 4 labels/wave/iter via 16-lane float4 groups; 64 labels/block -------
__global__ __launch_bounds__(256) void k_decode(const float* __restrict__ z,
                                                const int* __restrict__ eli,
                                                float* __restrict__ out, int L) {
    __shared__ float res[64];
    int t = threadIdx.x, wv = t >> 6, lane = t & 63;
    int g = lane >> 4, li = lane & 15;
    int base = blockIdx.x * 64;
#pragma unroll
    for (int it = 0; it < 4; ++it) {
        int l = base + wv * 16 + it * 4 + g;
        float p = 0.0f;
        if (l < L) {
            int a = __builtin_nontemporal_load(eli + l);
            int b = __builtin_nontemporal_load(eli + L + l);
            float4 va = *(const float4*)(z + (size_t)a * 64 + li * 4);
            float4 vb = *(const float4*)(z + (size_t)b * 64 + li * 4);
            p = va.x * vb.x;
            p = fmaf(va.y, vb.y, p);
            p = fmaf(va.z, vb.z, p);
            p = fmaf(va.w, vb.w, p);
        }
#pragma unroll
        for (int m = 1; m < 16; m <<= 1) p += __shfl_xor(p, m, 64);
        if (li == 0) res[wv * 16 + it * 4 + g] = p;
    }
    __syncthreads();
    if (t < 64 && base + t < L) out[base + t] = res[t];
}

extern "C" void kernel_launch(void* const* d_in, const int* in_sizes, int n_in,
                              void* d_out, int out_size, void* d_ws, size_t ws_size,
                              hipStream_t stream) {
    const float* x   = (const float*)d_in[0];        // [NN, 32]
    const float* ew  = (const float*)d_in[1];        // [NE]
    const int*   ei  = (const int*)d_in[2];          // [2, NE]
    const int*   eli = (const int*)d_in[3];          // [2, NL]
    const float* W1 = (const float*)d_in[4];  const float* b1 = (const float*)d_in[5];
    const float* W2 = (const float*)d_in[6];  const float* b2 = (const float*)d_in[7];
    const float* W3 = (const float*)d_in[8];  const float* b3 = (const float*)d_in[9];
    const float* W4 = (const float*)d_in[10]; const float* b4 = (const float*)d_in[11];
    const float* W5 = (const float*)d_in[12]; const float* b5 = (const float*)d_in[13];
    float* out = (float*)d_out;

    const int* src = ei;
    const int* dst = ei + NE;

    // ---- carve workspace (256B aligned) ----
    char* w = (char*)d_ws;
    size_t off = 0;
    auto carve = [&](size_t bytes) -> void* {
        void* p = w + off;
        off = (off + bytes + 255) & ~(size_t)255;
        return p;
    };
    float*     dinv   = (float*)carve(sizeof(float) * NN);
    int*       gcnt   = (int*)  carve(sizeof(int) * NBC);
    int*       rowptr = (int*)  carve(sizeof(int) * (NN + 1));
    int*       bbase  = (int*)  carve(sizeof(int) * (NBC + 1));
    int2*      csr    = (int2*) carve(sizeof(int2) * NE);
    // binned (28.8MB) aliases bufA (25.6MB): binned is dead before bufA's
    // first write (k_prop1x runs after k_build's last binned read).
    long long* binned = (long long*)carve(sizeof(long long) * (size_t)NBC * CAPC);
    float*     bufA   = (float*)binned;
    float*     bufB   = (float*)carve(sizeof(float) * (size_t)NN * 64);
    (void)ws_size; (void)n_in; (void)in_sizes; (void)out_size;

    const int TB = 256;
    int gW4 = (NN + 3) / 4;       // 4 nodes/block (wave per node)
    int gG  = (NN + 31) / 32;     // gemm: 32 nodes/block
    int gD  = (NL + 63) / 64;     // decode: 64 labels/block
    int gB  = (NE + EPB - 1) / EPB;

    // ---- graph preprocessing: block counting sort -> CSR + dinv + norm ----
    k_zero <<<2, 256, 0, stream>>>(gcnt, NBC);
    k_bin  <<<gB, TB, 0, stream>>>(src, dst, ew, gcnt, binned, NE);
    k_bases<<<1, 512, 0, stream>>>(gcnt, bbase, rowptr);
    k_build<<<NBC, TB, 0, stream>>>(gcnt, binned, bbase, csr, rowptr, dinv);
    k_norm <<<gW4, TB, 0, stream>>>(rowptr, csr, dinv, NN);

    // ---- layer 1: (A x) @ W1 + b1, relu ----
    k_prop1x<<<gW4, TB, 0, stream>>>(x, rowptr, csr, dinv, bufA, NN);
    k_gemm<32><<<gG, TB, 0, stream>>>(bufA, W1, b1, bufB, NN, 1);
    // ---- layers 2..4 ----
    k_gemm<64><<<gG, TB, 0, stream>>>(bufB, W2, nullptr, bufA, NN, 0);
    k_prop<<<gW4, TB, 0, stream>>>(bufA, rowptr, csr, dinv, b2, bufB, NN, 1);
    k_gemm<64><<<gG, TB, 0, stream>>>(bufB, W3, nullptr, bufA, NN, 0);
    k_prop<<<gW4, TB, 0, stream>>>(bufA, rowptr, csr, dinv, b3, bufB, NN, 1);
    k_gemm<64><<<gG, TB, 0, stream>>>(bufB, W4, nullptr, bufA, NN, 0);
    k_prop<<<gW4, TB, 0, stream>>>(bufA, rowptr, csr, dinv, b4, bufB, NN, 1);
    // ---- layer 5 (no relu) ----
    k_gemm<64><<<gG, TB, 0, stream>>>(bufB, W5, nullptr, bufA, NN, 0);
    k_prop<<<gW4, TB, 0, stream>>>(bufA, rowptr, csr, dinv, b5, bufB, NN, 0);

    // ---- decode ----
    k_decode<<<gD, TB, 0, stream>>>(bufB, eli, out, NL);
}

// Round 20
// 808.489 us; speedup vs baseline: 1.9169x; 1.2540x over previous
//
#include <hip/hip_runtime.h>
#include <hip/hip_bf16.h>

#define NN 100000
#define NE 3200000
#define NL 1000000
#define NBC 391                         // buckets (dst >> 8)
#define NPBC 256                        // nodes per bucket
#define CAPC 9216                       // per-bucket capacity (mean 8184, +11 sigma)
#define EPB 4096                        // edges per k_bin block

__device__ __forceinline__ long long nt_ll(const void* p) {
    return __builtin_nontemporal_load((const long long*)p);
}

// ---------------- zero int buffer ----------------
__global__ void k_zero(int* __restrict__ p, int n) {
    int i = blockIdx.x * blockDim.x + threadIdx.x;
    if (i < n) p[i] = 0;
}

// ------- block-local counting sort: 4096 edges -> 391 bucket runs, coalesced out -------
__global__ __launch_bounds__(256) void k_bin(const int* __restrict__ src,
                                             const int* __restrict__ dst,
                                             const float* __restrict__ w,
                                             int* __restrict__ gcnt,
                                             long long* __restrict__ binned,
                                             int e_cnt) {
    __shared__ long long sorted[EPB];          // 32 KB
    __shared__ unsigned short bkt[EPB];        // 8 KB
    __shared__ int hist[NBC], scn[NBC], cur[NBC], gbase[NBC];
    __shared__ int psum[256];
    int t = threadIdx.x;
    int e0 = blockIdx.x * EPB;
    int cnt = e_cnt - e0; if (cnt > EPB) cnt = EPB;

    for (int i = t; i < NBC; i += 256) hist[i] = 0;
    __syncthreads();
    for (int i = t; i < cnt; i += 256) {
        int d = __builtin_nontemporal_load(dst + e0 + i);
        atomicAdd(&hist[d >> 8], 1);
    }
    __syncthreads();
    int b0 = 2 * t, b1 = 2 * t + 1;
    int h0 = (b0 < NBC) ? hist[b0] : 0;
    int h1 = (b1 < NBC) ? hist[b1] : 0;
    psum[t] = h0 + h1;
    __syncthreads();
    for (int o = 1; o < 256; o <<= 1) {
        int v = (t >= o) ? psum[t - o] : 0;
        __syncthreads();
        psum[t] += v;
        __syncthreads();
    }
    int eb = psum[t] - (h0 + h1);
    if (b0 < NBC) { scn[b0] = eb; cur[b0] = eb; gbase[b0] = atomicAdd(&gcnt[b0], h0); }
    if (b1 < NBC) { scn[b1] = eb + h0; cur[b1] = eb + h0; gbase[b1] = atomicAdd(&gcnt[b1], h1); }
    __syncthreads();
    for (int i = t; i < cnt; i += 256) {
        int d = __builtin_nontemporal_load(dst + e0 + i);
        int s = __builtin_nontemporal_load(src + e0 + i);
        float wf = __builtin_nontemporal_load(w + e0 + i);
        int b = d >> 8;
        long long ent = (unsigned int)(s | ((d & 255) << 17)) |
                        ((long long)__float_as_int(wf) << 32);
        int r = atomicAdd(&cur[b], 1);
        sorted[r] = ent;
        bkt[r] = (unsigned short)b;
    }
    __syncthreads();
    for (int i = t; i < cnt; i += 256) {
        int b = bkt[i];
        int g = gbase[b] + (i - scn[b]);
        if (g < CAPC) binned[(size_t)b * CAPC + g] = sorted[i];
    }
}

// ------- exclusive scan of per-bucket totals -> bucketBase; rowptr[NN]=total -------
__global__ __launch_bounds__(512) void k_bases(const int* __restrict__ gcnt,
                                               int* __restrict__ bucketBase,
                                               int* __restrict__ rowptr) {
    __shared__ int part[512];
    int t = threadIdx.x;
    int T = 0;
    if (t < NBC) { T = gcnt[t]; if (T > CAPC) T = CAPC; }
    part[t] = T;
    __syncthreads();
    for (int off = 1; off < 512; off <<= 1) {
        int v = (t >= off) ? part[t - off] : 0;
        __syncthreads();
        part[t] += v;
        __syncthreads();
    }
    if (t < NBC) bucketBase[t] = part[t] - T;
    if (t == NBC - 1) { bucketBase[NBC] = part[t]; rowptr[NN] = part[t]; }
}

// ------- per-bucket two-pass: hist+deg, 256-scan, scatter -> csr/rowptr/dinv -------
__global__ __launch_bounds__(256) void k_build(const int* __restrict__ gcnt,
                                               const long long* __restrict__ binned,
                                               const int* __restrict__ bucketBase,
                                               int2* __restrict__ csr,
                                               int* __restrict__ rowptr,
                                               float* __restrict__ dinv) {
    __shared__ int hist[NPBC];
    __shared__ int scn[NPBC];
    __shared__ float degs[NPBC];
    int b = blockIdx.x, t = threadIdx.x;
    int node0 = b * NPBC;
    int nloc = NN - node0; if (nloc > NPBC) nloc = NPBC;
    hist[t] = 0; degs[t] = 0.0f;
    __syncthreads();
    int T = gcnt[b]; if (T > CAPC) T = CAPC;
    const long long* bp = binned + (size_t)b * CAPC;
    for (int i = t; i < T; i += 256) {
        long long v = nt_ll(bp + i);
        int dlow = (((unsigned)(int)v) >> 17) & 255;
        atomicAdd(&hist[dlow], 1);
        atomicAdd(&degs[dlow], __int_as_float((int)(v >> 32)));
    }
    __syncthreads();
    int h = hist[t];
    scn[t] = h;
    __syncthreads();
    for (int off = 1; off < 256; off <<= 1) {
        int v = (t >= off) ? scn[t - off] : 0;
        __syncthreads();
        scn[t] += v;
        __syncthreads();
    }
    int ex = scn[t] - h;
    int base = bucketBase[b];
    if (t < nloc) {
        rowptr[node0 + t] = base + ex;
        dinv[node0 + t] = 1.0f / sqrtf(1.0f + degs[t]);   // +1 = self-loop weight
    }
    __syncthreads();
    hist[t] = ex;                                  // hist becomes fill cursor
    __syncthreads();
    for (int i = t; i < T; i += 256) {
        long long v = nt_ll(bp + i);
        int xi = (int)v;
        int dlow = (((unsigned)xi) >> 17) & 255;
        int slot = atomicAdd(&hist[dlow], 1);
        int2 ent;
        ent.x = xi & 0x1FFFF;
        ent.y = (int)(v >> 32);
        csr[(size_t)base + slot] = ent;            // scatter within ~66KB window
    }
}

// ---------------- norm: csr.y := dinv[src]*w*dinv[dst] (in place, once) ---------------
__global__ __launch_bounds__(256) void k_norm(const int* __restrict__ rowptr,
                                              int2* __restrict__ csr,
                                              const float* __restrict__ dinv, int n) {
    int t = threadIdx.x, wv = t >> 6, lane = t & 63;
    int node = blockIdx.x * 4 + wv;
    if (node >= n) return;
    float di = dinv[node];
    int lo = rowptr[node], hi = rowptr[node + 1];
    for (int j = lo + lane; j < hi; j += 64) {
        int2 e = csr[j];
        e.y = __float_as_int(dinv[e.x] * __int_as_float(e.y) * di);
        csr[j] = e;
    }
}

// ---- propagate 32-ch x: wave/node, 8 lane-groups x float4, 4-deep MLP ----
__global__ __launch_bounds__(256) void k_prop1x(const float* __restrict__ x,
                                                const int* __restrict__ rowptr,
                                                const int2* __restrict__ csr,
                                                const float* __restrict__ dinv,
                                                float* __restrict__ out, int n) {
    int t = threadIdx.x, wv = t >> 6, lane = t & 63;
    int g = lane >> 3, li = lane & 7;          // 8 groups x 8 lanes; 8*4=32 ch
    int node = blockIdx.x * 4 + wv;
    if (node >= n) return;
    float di = dinv[node];
    int lo = rowptr[node], hi = rowptr[node + 1];
    float4 acc = make_float4(0.f, 0.f, 0.f, 0.f);
    int j = lo + g;
    for (; j + 24 < hi; j += 32) {             // 4 edges in flight per group
        int2 e0 = csr[j], e1 = csr[j + 8], e2 = csr[j + 16], e3 = csr[j + 24];
        float4 v0 = *(const float4*)(x + (size_t)e0.x * 32 + li * 4);
        float4 v1 = *(const float4*)(x + (size_t)e1.x * 32 + li * 4);
        float4 v2 = *(const float4*)(x + (size_t)e2.x * 32 + li * 4);
        float4 v3 = *(const float4*)(x + (size_t)e3.x * 32 + li * 4);
        float n0 = __int_as_float(e0.y), n1 = __int_as_float(e1.y);
        float n2 = __int_as_float(e2.y), n3 = __int_as_float(e3.y);
        acc.x = fmaf(n0, v0.x, acc.x); acc.y = fmaf(n0, v0.y, acc.y);
        acc.z = fmaf(n0, v0.z, acc.z); acc.w = fmaf(n0, v0.w, acc.w);
        acc.x = fmaf(n1, v1.x, acc.x); acc.y = fmaf(n1, v1.y, acc.y);
        acc.z = fmaf(n1, v1.z, acc.z); acc.w = fmaf(n1, v1.w, acc.w);
        acc.x = fmaf(n2, v2.x, acc.x); acc.y = fmaf(n2, v2.y, acc.y);
        acc.z = fmaf(n2, v2.z, acc.z); acc.w = fmaf(n2, v2.w, acc.w);
        acc.x = fmaf(n3, v3.x, acc.x); acc.y = fmaf(n3, v3.y, acc.y);
        acc.z = fmaf(n3, v3.z, acc.z); acc.w = fmaf(n3, v3.w, acc.w);
    }
    for (; j < hi; j += 8) {
        int2 e = csr[j];
        float4 v = *(const float4*)(x + (size_t)e.x * 32 + li * 4);
        float nm = __int_as_float(e.y);
        acc.x = fmaf(nm, v.x, acc.x); acc.y = fmaf(nm, v.y, acc.y);
        acc.z = fmaf(nm, v.z, acc.z); acc.w = fmaf(nm, v.w, acc.w);
    }
#pragma unroll
    for (int m = 8; m < 64; m <<= 1) {
        acc.x += __shfl_xor(acc.x, m, 64);
        acc.y += __shfl_xor(acc.y, m, 64);
        acc.z += __shfl_xor(acc.z, m, 64);
        acc.w += __shfl_xor(acc.w, m, 64);
    }
    if (g == 0) {
        float4 sv = *(const float4*)(x + (size_t)node * 32 + li * 4);
        float s = di * di;
        acc.x = fmaf(s, sv.x, acc.x); acc.y = fmaf(s, sv.y, acc.y);
        acc.z = fmaf(s, sv.z, acc.z); acc.w = fmaf(s, sv.w, acc.w);
        *(float4*)(out + (size_t)node * 32 + li * 4) = acc;
    }
}

// ---- fused layer-1 double GEMM: hw2 = relu(t1 @ W1 + b1) @ W2; 8 nodes/wave ----
__global__ __launch_bounds__(256) void k_fuse12(const float* __restrict__ t1,
                                                const float* __restrict__ W1,
                                                const float* __restrict__ b1,
                                                const float* __restrict__ W2,
                                                float* __restrict__ out, int n) {
    __shared__ float W1l[32 * 64];             // 8 KB
    __shared__ float W2l[64 * 64];             // 16 KB
    __shared__ float trow[4][64];
    int t = threadIdx.x;
    for (int i = t; i < 32 * 64; i += 256) W1l[i] = W1[i];
    for (int i = t; i < 64 * 64; i += 256) W2l[i] = W2[i];
    __syncthreads();
    int lane = t & 63, wv = t >> 6;
    float w1c[32];
#pragma unroll
    for (int k = 0; k < 32; ++k) w1c[k] = W1l[k * 64 + lane];
    float bs = b1[lane];
    int base = blockIdx.x * 32 + wv * 8;
#pragma unroll 1
    for (int nd = base; nd < base + 8; ++nd) {
        if (nd >= n) break;
        const float4* row4 = (const float4*)(t1 + (size_t)nd * 32);
        float acc = 0.0f;
#pragma unroll
        for (int k4 = 0; k4 < 8; ++k4) {
            float4 v = row4[k4];
            acc = fmaf(v.x, w1c[4 * k4 + 0], acc);
            acc = fmaf(v.y, w1c[4 * k4 + 1], acc);
            acc = fmaf(v.z, w1c[4 * k4 + 2], acc);
            acc = fmaf(v.w, w1c[4 * k4 + 3], acc);
        }
        acc = fmaxf(acc + bs, 0.0f);           // h2[nd][lane]
        trow[wv][lane] = acc;                  // wave-local LDS (in-order, no barrier)
        float acc2 = 0.0f;
#pragma unroll
        for (int c4 = 0; c4 < 16; ++c4) {
            float4 tv = *(const float4*)&trow[wv][c4 * 4];
            acc2 = fmaf(tv.x, W2l[(c4 * 4 + 0) * 64 + lane], acc2);
            acc2 = fmaf(tv.y, W2l[(c4 * 4 + 1) * 64 + lane], acc2);
            acc2 = fmaf(tv.z, W2l[(c4 * 4 + 2) * 64 + lane], acc2);
            acc2 = fmaf(tv.w, W2l[(c4 * 4 + 3) * 64 + lane], acc2);
        }
        out[(size_t)nd * 64 + lane] = acc2;    // hw2
    }
}

// -- fused prop+gemm: hw' = relu(A.hw + b) @ Wn; wave/node, 4 groups, 4-deep --
__global__ __launch_bounds__(256) void k_pg(const float* __restrict__ hw,
                                            const int* __restrict__ rowptr,
                                            const int2* __restrict__ csr,
                                            const float* __restrict__ dinv,
                                            const float* __restrict__ bias,
                                            const float* __restrict__ Wn,
                                            float* __restrict__ out, int n) {
    __shared__ float Wl[64 * 64];              // 16 KB (next layer W)
    __shared__ float trow[4][64];
    int t = threadIdx.x;
    for (int i = t; i < 64 * 64; i += 256) Wl[i] = Wn[i];
    __syncthreads();
    int lane = t & 63, wv = t >> 6;
    int g = lane >> 4, li = lane & 15;
    int node = blockIdx.x * 4 + wv;
    if (node >= n) return;
    float di = dinv[node];
    int lo = rowptr[node], hi = rowptr[node + 1];
    float4 acc = make_float4(0.f, 0.f, 0.f, 0.f);
    int j = lo + g;
    for (; j + 12 < hi; j += 16) {             // 4 edges in flight per group
        int2 e0 = csr[j], e1 = csr[j + 4], e2 = csr[j + 8], e3 = csr[j + 12];
        float4 v0 = *(const float4*)(hw + (size_t)e0.x * 64 + li * 4);
        float4 v1 = *(const float4*)(hw + (size_t)e1.x * 64 + li * 4);
        float4 v2 = *(const float4*)(hw + (size_t)e2.x * 64 + li * 4);
        float4 v3 = *(const float4*)(hw + (size_t)e3.x * 64 + li * 4);
        float n0 = __int_as_float(e0.y), n1 = __int_as_float(e1.y);
        float n2 = __int_as_float(e2.y), n3 = __int_as_float(e3.y);
        acc.x = fmaf(n0, v0.x, acc.x); acc.y = fmaf(n0, v0.y, acc.y);
        acc.z = fmaf(n0, v0.z, acc.z); acc.w = fmaf(n0, v0.w, acc.w);
        acc.x = fmaf(n1, v1.x, acc.x); acc.y = fmaf(n1, v1.y, acc.y);
        acc.z = fmaf(n1, v1.z, acc.z); acc.w = fmaf(n1, v1.w, acc.w);
        acc.x = fmaf(n2, v2.x, acc.x); acc.y = fmaf(n2, v2.y, acc.y);
        acc.z = fmaf(n2, v2.z, acc.z); acc.w = fmaf(n2, v2.w, acc.w);
        acc.x = fmaf(n3, v3.x, acc.x); acc.y = fmaf(n3, v3.y, acc.y);
        acc.z = fmaf(n3, v3.z, acc.z); acc.w = fmaf(n3, v3.w, acc.w);
    }
    for (; j < hi; j += 4) {
        int2 e = csr[j];
        float4 v = *(const float4*)(hw + (size_t)e.x * 64 + li * 4);
        float nm = __int_as_float(e.y);
        acc.x = fmaf(nm, v.x, acc.x); acc.y = fmaf(nm, v.y, acc.y);
        acc.z = fmaf(nm, v.z, acc.z); acc.w = fmaf(nm, v.w, acc.w);
    }
#pragma unroll
    for (int m = 16; m < 64; m <<= 1) {        // butterfly: ALL lanes get channel sums
        acc.x += __shfl_xor(acc.x, m, 64);
        acc.y += __shfl_xor(acc.y, m, 64);
        acc.z += __shfl_xor(acc.z, m, 64);
        acc.w += __shfl_xor(acc.w, m, 64);
    }
    {   // self + bias + relu (all lanes compute identical values per channel)
        float4 sv = *(const float4*)(hw + (size_t)node * 64 + li * 4);
        float s = di * di;
        acc.x = fmaf(s, sv.x, acc.x); acc.y = fmaf(s, sv.y, acc.y);
        acc.z = fmaf(s, sv.z, acc.z); acc.w = fmaf(s, sv.w, acc.w);
        const float4 bv = *(const float4*)(bias + li * 4);
        acc.x = fmaxf(acc.x + bv.x, 0.f); acc.y = fmaxf(acc.y + bv.y, 0.f);
        acc.z = fmaxf(acc.z + bv.z, 0.f); acc.w = fmaxf(acc.w + bv.w, 0.f);
    }
    if (g == 0) *(float4*)&trow[wv][li * 4] = acc;   // wave-local, in-order
    float acc2 = 0.0f;
#pragma unroll
    for (int c4 = 0; c4 < 16; ++c4) {
        float4 tv = *(const float4*)&trow[wv][c4 * 4];
        acc2 = fmaf(tv.x, Wl[(c4 * 4 + 0) * 64 + lane], acc2);
        acc2 = fmaf(tv.y, Wl[(c4 * 4 + 1) * 64 + lane], acc2);
        acc2 = fmaf(tv.z, Wl[(c4 * 4 + 2) * 64 + lane], acc2);
        acc2 = fmaf(tv.w, Wl[(c4 * 4 + 3) * 64 + lane], acc2);
    }
    out[(size_t)node * 64 + lane] = acc2;      // hw next, coalesced
}

// -- final propagate (no gemm after): z = A.hw + b (no relu); 4-deep --
__global__ __launch_bounds__(256) void k_prop(const float* __restrict__ hw,
                                              const int* __restrict__ rowptr,
                                              const int2* __restrict__ csr,
                                              const float* __restrict__ dinv,
                                              const float* __restrict__ bias,
                                              float* __restrict__ out, int n) {
    int t = threadIdx.x;
    int lane = t & 63, wv = t >> 6;
    int g = lane >> 4, li = lane & 15;
    int node = blockIdx.x * 4 + wv;
    if (node >= n) return;
    float di = dinv[node];
    int lo = rowptr[node], hi = rowptr[node + 1];
    float4 acc = make_float4(0.f, 0.f, 0.f, 0.f);
    int j = lo + g;
    for (; j + 12 < hi; j += 16) {
        int2 e0 = csr[j], e1 = csr[j + 4], e2 = csr[j + 8], e3 = csr[j + 12];
        float4 v0 = *(const float4*)(hw + (size_t)e0.x * 64 + li * 4);
        float4 v1 = *(const float4*)(hw + (size_t)e1.x * 64 + li * 4);
        float4 v2 = *(const float4*)(hw + (size_t)e2.x * 64 + li * 4);
        float4 v3 = *(const float4*)(hw + (size_t)e3.x * 64 + li * 4);
        float n0 = __int_as_float(e0.y), n1 = __int_as_float(e1.y);
        float n2 = __int_as_float(e2.y), n3 = __int_as_float(e3.y);
        acc.x = fmaf(n0, v0.x, acc.x); acc.y = fmaf(n0, v0.y, acc.y);
        acc.z = fmaf(n0, v0.z, acc.z); acc.w = fmaf(n0, v0.w, acc.w);
        acc.x = fmaf(n1, v1.x, acc.x); acc.y = fmaf(n1, v1.y, acc.y);
        acc.z = fmaf(n1, v1.z, acc.z); acc.w = fmaf(n1, v1.w, acc.w);
        acc.x = fmaf(n2, v2.x, acc.x); acc.y = fmaf(n2, v2.y, acc.y);
        acc.z = fmaf(n2, v2.z, acc.z); acc.w = fmaf(n2, v2.w, acc.w);
        acc.x = fmaf(n3, v3.x, acc.x); acc.y = fmaf(n3, v3.y, acc.y);
        acc.z = fmaf(n3, v3.z, acc.z); acc.w = fmaf(n3, v3.w, acc.w);
    }
    for (; j < hi; j += 4) {
        int2 e = csr[j];
        float4 v = *(const float4*)(hw + (size_t)e.x * 64 + li * 4);
        float nm = __int_as_float(e.y);
        acc.x = fmaf(nm, v.x, acc.x); acc.y = fmaf(nm, v.y, acc.y);
        acc.z = fmaf(nm, v.z, acc.z); acc.w = fmaf(nm, v.w, acc.w);
    }
#pragma unroll
    for (int m = 16; m < 64; m <<= 1) {
        acc.x += __shfl_xor(acc.x, m, 64);
        acc.y += __shfl_xor(acc.y, m, 64);
        acc.z += __shfl_xor(acc.z, m, 64);
        acc.w += __shfl_xor(acc.w, m, 64);
    }
    if (g == 0) {
        float4 sv = *(const float4*)(hw + (size_t)node * 64 + li * 4);
        float s = di * di;
        acc.x = fmaf(s, sv.x, acc.x); acc.y = fmaf(s, sv.y, acc.y);
        acc.z = fmaf(s, sv.z, acc.z); acc.w = fmaf(s, sv.w, acc.w);
        const float4 bv = *(const float4*)(bias + li * 4);
        acc.x += bv.x; acc.y += bv.y; acc.z += bv.z; acc.w += bv.w;
        *(float4*)(out + (size_t)node * 64 + li * 4) = acc;
    }
}

// ------- decoder: 4 labels/wave/iter via 16-lane float4 groups; 64 labels/block -------
__global__ __launch_bounds__(256) void k_decode(const float* __restrict__ z,
                                                const int* __restrict__ eli,
                                                float* __restrict__ out, int L) {
    __shared__ float res[64];
    int t = threadIdx.x, wv = t >> 6, lane = t & 63;
    int g = lane >> 4, li = lane & 15;
    int base = blockIdx.x * 64;
#pragma unroll
    for (int it = 0; it < 4; ++it) {
        int l = base + wv * 16 + it * 4 + g;
        float p = 0.0f;
        if (l < L) {
            int a = __builtin_nontemporal_load(eli + l);
            int b = __builtin_nontemporal_load(eli + L + l);
            float4 va = *(const float4*)(z + (size_t)a * 64 + li * 4);
            float4 vb = *(const float4*)(z + (size_t)b * 64 + li * 4);
            p = va.x * vb.x;
            p = fmaf(va.y, vb.y, p);
            p = fmaf(va.z, vb.z, p);
            p = fmaf(va.w, vb.w, p);
        }
#pragma unroll
        for (int m = 1; m < 16; m <<= 1) p += __shfl_xor(p, m, 64);
        if (li == 0) res[wv * 16 + it * 4 + g] = p;
    }
    __syncthreads();
    if (t < 64 && base + t < L) out[base + t] = res[t];
}

extern "C" void kernel_launch(void* const* d_in, const int* in_sizes, int n_in,
                              void* d_out, int out_size, void* d_ws, size_t ws_size,
                              hipStream_t stream) {
    const float* x   = (const float*)d_in[0];        // [NN, 32]
    const float* ew  = (const float*)d_in[1];        // [NE]
    const int*   ei  = (const int*)d_in[2];          // [2, NE]
    const int*   eli = (const int*)d_in[3];          // [2, NL]
    const float* W1 = (const float*)d_in[4];  const float* b1 = (const float*)d_in[5];
    const float* W2 = (const float*)d_in[6];  const float* b2 = (const float*)d_in[7];
    const float* W3 = (const float*)d_in[8];  const float* b3 = (const float*)d_in[9];
    const float* W4 = (const float*)d_in[10]; const float* b4 = (const float*)d_in[11];
    const float* W5 = (const float*)d_in[12]; const float* b5 = (const float*)d_in[13];
    float* out = (float*)d_out;

    const int* src = ei;
    const int* dst = ei + NE;

    // ---- carve workspace (256B aligned) ----
    char* w = (char*)d_ws;
    size_t off = 0;
    auto carve = [&](size_t bytes) -> void* {
        void* p = w + off;
        off = (off + bytes + 255) & ~(size_t)255;
        return p;
    };
    float*     dinv   = (float*)carve(sizeof(float) * NN);
    int*       gcnt   = (int*)  carve(sizeof(int) * NBC);
    int*       rowptr = (int*)  carve(sizeof(int) * (NN + 1));
    int*       bbase  = (int*)  carve(sizeof(int) * (NBC + 1));
    int2*      csr    = (int2*) carve(sizeof(int2) * NE);
    // binned (28.8MB) aliases bufA (25.6MB): binned is dead before bufA's
    // first write (k_prop1x runs after k_build's last binned read).
    long long* binned = (long long*)carve(sizeof(long long) * (size_t)NBC * CAPC);
    float*     bufA   = (float*)binned;
    float*     bufB   = (float*)carve(sizeof(float) * (size_t)NN * 64);
    (void)ws_size; (void)n_in; (void)in_sizes; (void)out_size;

    const int TB = 256;
    int gW4 = (NN + 3) / 4;       // 4 nodes/block (wave per node)
    int gG  = (NN + 31) / 32;     // fuse12: 32 nodes/block
    int gD  = (NL + 63) / 64;     // decode: 64 labels/block
    int gB  = (NE + EPB - 1) / EPB;

    // ---- graph preprocessing: block counting sort -> CSR + dinv + norm ----
    k_zero <<<2, 256, 0, stream>>>(gcnt, NBC);
    k_bin  <<<gB, TB, 0, stream>>>(src, dst, ew, gcnt, binned, NE);
    k_bases<<<1, 512, 0, stream>>>(gcnt, bbase, rowptr);
    k_build<<<NBC, TB, 0, stream>>>(gcnt, binned, bbase, csr, rowptr, dinv);
    k_norm <<<gW4, TB, 0, stream>>>(rowptr, csr, dinv, NN);

    // ---- layer 1: t1 = A.x ; hw2 = relu(t1@W1+b1)@W2 ----
    k_prop1x<<<gW4, TB, 0, stream>>>(x, rowptr, csr, dinv, bufA, NN);
    k_fuse12<<<gG, TB, 0, stream>>>(bufA, W1, b1, W2, bufB, NN);
    // ---- fused layers: hw3, hw4, hw5 ----
    k_pg<<<gW4, TB, 0, stream>>>(bufB, rowptr, csr, dinv, b2, W3, bufA, NN);
    k_pg<<<gW4, TB, 0, stream>>>(bufA, rowptr, csr, dinv, b3, W4, bufB, NN);
    k_pg<<<gW4, TB, 0, stream>>>(bufB, rowptr, csr, dinv, b4, W5, bufA, NN);
    // ---- final: z = A.hw5 + b5 ----
    k_prop<<<gW4, TB, 0, stream>>>(bufA, rowptr, csr, dinv, b5, bufB, NN);

    // ---- decode ----
    k_decode<<<gD, TB, 0, stream>>>(bufB, eli, out, NL);
}